// Round 15
// baseline (503.544 us; speedup 1.0000x reference)
//
#include <hip/hip_runtime.h>
#include <hip/hip_bf16.h>
#include <math.h>
#include <stdint.h>

// Problem constants (CoconutPPO): B=128, H=4096, R=256, M=500000, K=3
#define BB 128
#define HH 4096
#define RR 256
#define M_TOT 500000
#define CHUNK 1024
#define NCHUNK ((M_TOT + CHUNK - 1) / CHUNK)   // 489
#define NPAD (NCHUNK * CHUNK)                  // 500736
#define TINYF 1.17549435e-38f

// d_out layout (floats, concatenated in return order)
#define OFF_LATENT 0
#define OFF_POS    524288
#define OFF_ACT    557056
#define OFF_LP     557184
#define OFF_VAL    557312
#define OFF_ENT    557440

typedef __attribute__((ext_vector_type(8))) short bf16x8;
typedef __attribute__((ext_vector_type(4))) float f32x4;

// ---------------------------------------------------------------- helpers
__device__ __forceinline__ bool better(float a, int ia, float b, int ib) {
  return a > b || (a == b && ia < ib);
}
__device__ __forceinline__ void ins4_nd(float s, int id, float (&vs)[4], int (&vi)[4]) {
  if (better(s, id, vs[3], vi[3])) {
    vs[3] = s; vi[3] = id;
    if (better(vs[3], vi[3], vs[2], vi[2])) { float a=vs[3]; vs[3]=vs[2]; vs[2]=a; int x=vi[3]; vi[3]=vi[2]; vi[2]=x; }
    if (better(vs[2], vi[2], vs[1], vi[1])) { float a=vs[2]; vs[2]=vs[1]; vs[1]=a; int x=vi[2]; vi[2]=vi[1]; vi[1]=x; }
    if (better(vs[1], vi[1], vs[0], vi[0])) { float a=vs[1]; vs[1]=vs[0]; vs[0]=a; int x=vi[1]; vi[1]=vi[0]; vi[0]=x; }
  }
}
__device__ __forceinline__ void ins4(float s, int id, float (&vs)[4], int (&vi)[4]) {
  if (id == vi[0] || id == vi[1] || id == vi[2] || id == vi[3]) return;
  ins4_nd(s, id, vs, vi);
}
__device__ __forceinline__ void ins3(float s, int id, float (&vs)[3], int (&vi)[3]) {
  if (id == vi[0] || id == vi[1] || id == vi[2]) return;
  if (better(s, id, vs[2], vi[2])) {
    vs[2] = s; vi[2] = id;
    if (better(vs[2], vi[2], vs[1], vi[1])) { float a=vs[2]; vs[2]=vs[1]; vs[1]=a; int x=vi[2]; vi[2]=vi[1]; vi[1]=x; }
    if (better(vs[1], vi[1], vs[0], vi[0])) { float a=vs[1]; vs[1]=vs[0]; vs[0]=a; int x=vi[1]; vi[1]=vi[0]; vi[0]=x; }
  }
}
__device__ __forceinline__ void ins8(float s, int id, float (&vs)[8], int (&vi)[8]) {
#pragma unroll
  for (int q = 0; q < 8; ++q) if (id == vi[q]) return;
  if (!better(s, id, vs[7], vi[7])) return;
  vs[7] = s; vi[7] = id;
#pragma unroll
  for (int q = 7; q > 0; --q)
    if (better(vs[q], vi[q], vs[q-1], vi[q-1])) {
      float a = vs[q]; vs[q] = vs[q-1]; vs[q-1] = a;
      int x = vi[q]; vi[q] = vi[q-1]; vi[q-1] = x;
    }
}

// RNE f32 -> bf16 (bit arithmetic; matches hardware/NumPy RNE)
__device__ __forceinline__ uint32_t rne_u(float x) {
  uint32_t u = __float_as_uint(x);
  return (u + 0x7fffu + ((u >> 16) & 1u)) >> 16;
}
__device__ __forceinline__ uint32_t pk_bf16(float lo, float hi) {
  return rne_u(lo) | (rne_u(hi) << 16);
}

// async global->LDS (wave-uniform LDS base, per-lane global source)
__device__ __forceinline__ void load_lds16(const void* g, void* l) {
  __builtin_amdgcn_global_load_lds((const __attribute__((address_space(1))) void*)g,
                                   (__attribute__((address_space(3))) void*)l, 16, 0, 0);
}

#define TF_ROUND(r) { x0 += x1; x1 = (x1 << (r)) | (x1 >> (32 - (r))); x1 ^= x0; }
__device__ __forceinline__ void threefry2x32(uint32_t k0, uint32_t k1,
                                             uint32_t x0, uint32_t x1,
                                             uint32_t& o0, uint32_t& o1) {
  const uint32_t ks2 = k0 ^ k1 ^ 0x1BD11BDAu;
  x0 += k0; x1 += k1;
  TF_ROUND(13) TF_ROUND(15) TF_ROUND(26) TF_ROUND(6)
  x0 += k1; x1 += ks2 + 1u;
  TF_ROUND(17) TF_ROUND(29) TF_ROUND(16) TF_ROUND(24)
  x0 += ks2; x1 += k0 + 2u;
  TF_ROUND(13) TF_ROUND(15) TF_ROUND(26) TF_ROUND(6)
  x0 += k0; x1 += k1 + 3u;
  TF_ROUND(17) TF_ROUND(29) TF_ROUND(16) TF_ROUND(24)
  x0 += k1; x1 += ks2 + 4u;
  TF_ROUND(13) TF_ROUND(15) TF_ROUND(26) TF_ROUND(6)
  x0 += ks2; x1 += k0 + 5u;
  o0 = x0; o1 = x1;
}

__device__ __forceinline__ float gumbel_from_bits(uint32_t bits) {
  const uint32_t fb = (bits >> 9) | 0x3f800000u;
  const float fl = __uint_as_float(fb) - 1.0f;
  const float u = fmaxf(TINYF, fl * (1.0f - TINYF) + TINYF);
  return -logf(-logf(u));
}

// ---------------------------------------------------------------- generic fp32 GEMM
// MODE 0: partial slab per blockIdx.z (no bias); 1: bias; 2: bias+relu.
template<int MODE>
__global__ __launch_bounds__(256)
void gemm_tile(const float* __restrict__ A, const float* __restrict__ Bw,
               const float* __restrict__ bias, float* __restrict__ C,
               int Mr, int Nc, int K, int klen) {
  __shared__ float As[16][68];
  __shared__ float Bs[16][68];
  const int col0 = blockIdx.x * 64;
  const int row0 = blockIdx.y * 64;
  const int k0 = blockIdx.z * klen;
  const int t = threadIdx.x;
  const int tc = t & 15, tr = t >> 4;
  float acc[4][4] = {};
  for (int kk = k0; kk < k0 + klen; kk += 16) {
    {
      const int r = t >> 2, c4 = (t & 3) << 2;
      const float4 v = *reinterpret_cast<const float4*>(A + (size_t)(row0 + r) * K + kk + c4);
      As[c4 + 0][r] = v.x; As[c4 + 1][r] = v.y; As[c4 + 2][r] = v.z; As[c4 + 3][r] = v.w;
    }
    {
      const int kr = t >> 4, c4 = (t & 15) << 2;
      const float4 v = *reinterpret_cast<const float4*>(Bw + (size_t)(kk + kr) * Nc + col0 + c4);
      *reinterpret_cast<float4*>(&Bs[kr][c4]) = v;
    }
    __syncthreads();
#pragma unroll
    for (int k = 0; k < 16; ++k) {
      const float4 a4 = *reinterpret_cast<const float4*>(&As[k][tr * 4]);
      const float4 b4 = *reinterpret_cast<const float4*>(&Bs[k][tc * 4]);
      float a[4] = {a4.x, a4.y, a4.z, a4.w};
      float b[4] = {b4.x, b4.y, b4.z, b4.w};
#pragma unroll
      for (int i = 0; i < 4; ++i)
#pragma unroll
        for (int j = 0; j < 4; ++j) acc[i][j] += a[i] * b[j];
    }
    __syncthreads();
  }
  float* Cp = C + (MODE == 0 ? (size_t)blockIdx.z * Mr * Nc : (size_t)0);
#pragma unroll
  for (int i = 0; i < 4; ++i) {
    const int row = row0 + tr * 4 + i;
#pragma unroll
    for (int j = 0; j < 4; ++j) {
      const int col = col0 + tc * 4 + j;
      float v = acc[i][j];
      if (MODE >= 1) v += bias[col];
      if (MODE == 2) v = fmaxf(v, 0.0f);
      Cp[(size_t)row * Nc + col] = v;
    }
  }
}

// ---------------------------------------------------------------- combines
template<int Z, bool RELU>
__global__ void combine_z(const float* __restrict__ src, const float* __restrict__ bias,
                          float* __restrict__ dst, int total, int mask) {
  const int i = blockIdx.x * 256 + threadIdx.x;
  float v = bias[i & mask];
#pragma unroll
  for (int z = 0; z < Z; ++z) v += src[(size_t)z * total + i];
  dst[i] = RELU ? fmaxf(v, 0.0f) : v;
}

__global__ __launch_bounds__(256)
void combine_r0(const float* __restrict__ r0p, const float* __restrict__ b2,
                float* __restrict__ r0, float* __restrict__ rnorm,
                uint32_t* __restrict__ rnbf) {
  const int b = blockIdx.x, t = threadIdx.x;
  __shared__ float red[256];
  __shared__ float vtmp[256];
  float v = b2[t];
#pragma unroll
  for (int z = 0; z < 8; ++z) v += r0p[z * 32768 + b * 256 + t];
  r0[b * 256 + t] = v;
  red[t] = v * v;
  __syncthreads();
  for (int s = 128; s > 0; s >>= 1) { if (t < s) red[t] += red[t + s]; __syncthreads(); }
  const float inv = 1.0f / fmaxf(sqrtf(red[0]), 1e-12f);
  const float vn = v * inv;
  rnorm[b * 256 + t] = vn;
  if (rnbf) {
    vtmp[t] = vn;
    __syncthreads();
    if (t < 128) rnbf[b * 128 + t] = pk_bf16(vtmp[2 * t], vtmp[2 * t + 1]);
  }
}

// ---------------------------------------------------------------- prep pass (path A)
// One wave per row, grid-stride. Reads fp32 bank (coalesced 1KB/row), writes
// PRE-SCALED bf16 row (bank[m]*wscale_m), PRE-SWIZZLED (16B chunk c at byte
// offset (c ^ (m&7))*16).
__global__ __launch_bounds__(256)
void prep_bank(const float* __restrict__ bank, const float* __restrict__ vals,
               uint32_t* __restrict__ bankbf) {
  const int lane = threadIdx.x & 63;
  const int wid = blockIdx.x * 4 + (threadIdx.x >> 6);
  const int nw = gridDim.x * 4;
  for (int m = wid; m < NPAD; m += nw) {
    float4 v = make_float4(0.f, 0.f, 0.f, 0.f);
    float vv = 0.0f;
    if (m < M_TOT) {
      v = *reinterpret_cast<const float4*>(bank + (size_t)m * 256 + lane * 4);
      vv = vals[m];                       // wave-uniform address -> 1 transaction
    }
    float s = v.x * v.x + v.y * v.y + v.z * v.z + v.w * v.w;
#pragma unroll
    for (int msk = 1; msk < 64; msk <<= 1) s += __shfl_xor(s, msk);
    const float wsc = (vv + 1e-8f) / fmaxf(sqrtf(s), 1e-12f);
    uint2 p;
    p.x = pk_bf16(v.x * wsc, v.y * wsc);
    p.y = pk_bf16(v.z * wsc, v.w * wsc);
    const int c = lane >> 1;
    *reinterpret_cast<uint2*>(
        reinterpret_cast<char*>(bankbf) + (size_t)m * 512 +
        (((c ^ (m & 7)) << 4) + (lane & 1) * 8)) = p;
  }
}

// ---------------------------------------------------------------- MFMA sims (path A)
// 512 thr / 8 waves, 64 KB LDS (4 bufs x 32 rows) -> 2 blocks/CU, 16 waves/CU.
// 489 blocks = one balanced scheduling wave. 32 subs of 32 rows; 3-deep
// counted-vmcnt pipeline (2 async loads/wave/sub; waits vmcnt(4)/(2)/(0) --
// never drain to 0 mid-loop). Each wave owns ONE 16-row batch set (Bf = 32
// VGPR) and all 32 m-rows.
__global__ __launch_bounds__(512, 4)
void sims_topk_a(const uint32_t* __restrict__ rnbf, const uint32_t* __restrict__ bankbf,
                 float* __restrict__ cand_s, int* __restrict__ cand_i) {
  __shared__ __align__(16) unsigned short tA[4][32 * 256];   // 4 x 16 KB

  const int t = threadIdx.x;
  const int lane = t & 63;
  const int w = t >> 6;            // wave 0..7 -> batch rows w*16..w*16+15
  const int fr = lane & 15;
  const int fq = lane >> 4;        // 0..3 (k-group)

  // ---- B-frags (one batch set per wave) from bf16 rnorm (row-major packed)
  bf16x8 Bf[8];
  {
    const uint4* rp = reinterpret_cast<const uint4*>(rnbf + (size_t)(w * 16 + fr) * 128);
#pragma unroll
    for (int ks = 0; ks < 8; ++ks) {
      uint4 u = rp[ks * 4 + fq];
      Bf[ks] = *reinterpret_cast<bf16x8*>(&u);
    }
  }

  float ts[4]; int ti[4];
#pragma unroll
  for (int q = 0; q < 4; ++q) { ts[q] = -INFINITY; ti[q] = 0x7ffffff0 + q; }

  const char* bb = reinterpret_cast<const char*>(bankbf);

  // issue one sub's staging (2 x 1KB per wave; row-pairs p = w*2+i)
  auto issue = [&](int sub) {
    const int mb = blockIdx.x * CHUNK + sub * 32;
    const int buf = sub & 3;
#pragma unroll
    for (int i = 0; i < 2; ++i) {
      const int p = w * 2 + i;     // row-pair 0..15 (2 rows x 512B)
      load_lds16(bb + (size_t)(mb + p * 2) * 512 + lane * 16,
                 reinterpret_cast<char*>(tA[buf]) + p * 1024);
    }
  };

  issue(0); issue(1); issue(2);
  asm volatile("s_waitcnt vmcnt(4)" ::: "memory");   // Bf + sub0 landed
  __builtin_amdgcn_s_barrier();

  for (int sub = 0; sub < 32; ++sub) {
    if (sub + 3 < 32) issue(sub + 3);
    const int m_base = blockIdx.x * CHUNK + sub * 32;
    const unsigned short* tc = tA[sub & 3];

    // ---- MFMA: 32 mem rows x 16 batch rows (this wave's set)
    f32x4 acc[2];
#pragma unroll
    for (int mt = 0; mt < 2; ++mt) acc[mt] = (f32x4){0.f, 0.f, 0.f, 0.f};
#pragma unroll
    for (int ks = 0; ks < 8; ++ks) {
      const int kc = ks * 4 + fq;
#pragma unroll
      for (int mt = 0; mt < 2; ++mt) {
        const int rA = mt * 16 + fr;
        const bf16x8 a = *reinterpret_cast<const bf16x8*>(
            tc + rA * 256 + ((kc ^ (rA & 7)) << 3));
        acc[mt] = __builtin_amdgcn_mfma_f32_16x16x32_bf16(a, Bf[ks], acc[mt], 0, 0, 0);
      }
    }
    // ---- epilogue: prescaled scores -> per-lane top-4
#pragma unroll
    for (int mt = 0; mt < 2; ++mt)
#pragma unroll
      for (int j = 0; j < 4; ++j) {
        const int ml = mt * 16 + fq * 4 + j;
        const int mm = m_base + ml;
        if (mm < M_TOT) ins4_nd(acc[mt][j], mm, ts, ti);
      }

    // ---- counted wait: only require sub+1 landed; keep newer loads in flight
    if (sub < 29) {
      asm volatile("s_waitcnt vmcnt(4)" ::: "memory");
      __builtin_amdgcn_s_barrier();
    } else if (sub == 29) {
      asm volatile("s_waitcnt vmcnt(2)" ::: "memory");
      __builtin_amdgcn_s_barrier();
    } else if (sub == 30) {
      asm volatile("s_waitcnt vmcnt(0)" ::: "memory");
      __builtin_amdgcn_s_barrier();
    }
  }

  // merge the 4 fq-lane groups sharing each batch row (snapshot butterfly)
#pragma unroll
  for (int mask = 16; mask < 64; mask <<= 1) {
    float os[4]; int oi[4];
#pragma unroll
    for (int q = 0; q < 4; ++q) {
      os[q] = __shfl_xor(ts[q], mask);
      oi[q] = __shfl_xor(ti[q], mask);
    }
#pragma unroll
    for (int q = 0; q < 4; ++q) ins4(os[q], oi[q], ts, ti);
  }
  if (fq == 0) {
    const int b = w * 16 + fr;
    const size_t base = ((size_t)b * NCHUNK + blockIdx.x) * 4;
#pragma unroll
    for (int q = 0; q < 4; ++q) { cand_s[base + q] = ts[q]; cand_i[base + q] = ti[q]; }
  }
}

// ---------------------------------------------------------------- MFMA sims (path B fallback, fp32 single pass)
__global__ __launch_bounds__(256, 4)
void sims_topk_b(const float* __restrict__ rnorm, const float* __restrict__ bank,
                 const float* __restrict__ vals, float* __restrict__ cand_s,
                 int* __restrict__ cand_i) {
  __shared__ __align__(16) unsigned short tA[64 * 256];
  __shared__ float wscaleL[64];

  const int t = threadIdx.x;
  const int lane = t & 63;
  const int w = t >> 6;
  const int fr = lane & 15;
  const int fq = lane >> 4;

  bf16x8 Bf[2][8];
#pragma unroll
  for (int set = 0; set < 2; ++set) {
    const float* rp = rnorm + (size_t)(set * 64 + w * 16 + fr) * 256 + fq * 8;
#pragma unroll
    for (int ks = 0; ks < 8; ++ks) {
      const float4 x0 = *reinterpret_cast<const float4*>(rp + ks * 32);
      const float4 x1 = *reinterpret_cast<const float4*>(rp + ks * 32 + 4);
      uint4 pk;
      pk.x = pk_bf16(x0.x, x0.y);
      pk.y = pk_bf16(x0.z, x0.w);
      pk.z = pk_bf16(x1.x, x1.y);
      pk.w = pk_bf16(x1.z, x1.w);
      Bf[set][ks] = *reinterpret_cast<bf16x8*>(&pk);
    }
  }

  float ts[2][4]; int ti[2][4];
#pragma unroll
  for (int set = 0; set < 2; ++set)
#pragma unroll
    for (int q = 0; q < 4; ++q) { ts[set][q] = -INFINITY; ti[set][q] = 0x7ffffff0 + q; }

  for (int sub = 0; sub < 16; ++sub) {
    const int m_base = blockIdx.x * CHUNK + sub * 64;
#pragma unroll 4
    for (int i = 0; i < 16; ++i) {
      const int r = i * 4 + w;
      const int m = m_base + r;
      float4 v = make_float4(0.f, 0.f, 0.f, 0.f);
      if (m < M_TOT)
        v = *reinterpret_cast<const float4*>(bank + (size_t)m * 256 + lane * 4);
      float s = v.x * v.x + v.y * v.y + v.z * v.z + v.w * v.w;
#pragma unroll
      for (int msk = 1; msk < 64; msk <<= 1) s += __shfl_xor(s, msk);
      const uint32_t p0 = pk_bf16(v.x, v.y);
      const uint32_t p1 = pk_bf16(v.z, v.w);
      const int cc = lane >> 1, h = lane & 1;
      uint32_t* dst = reinterpret_cast<uint32_t*>(
          tA + (size_t)r * 256 + (((cc ^ (r & 7)) << 3) + h * 4));
      dst[0] = p0; dst[1] = p1;
      if (lane == 0) {
        const float vv = (m < M_TOT) ? vals[m] : 0.0f;
        wscaleL[r] = (vv + 1e-8f) / fmaxf(sqrtf(s), 1e-12f);
      }
    }
    __syncthreads();

    f32x4 acc[2][4];
#pragma unroll
    for (int set = 0; set < 2; ++set)
#pragma unroll
      for (int mt = 0; mt < 4; ++mt) acc[set][mt] = (f32x4){0.f, 0.f, 0.f, 0.f};
#pragma unroll
    for (int ks = 0; ks < 8; ++ks) {
      const int kc = ks * 4 + fq;
#pragma unroll
      for (int mt = 0; mt < 4; ++mt) {
        const int rA = mt * 16 + fr;
        const bf16x8 a = *reinterpret_cast<const bf16x8*>(tA + rA * 256 + ((kc ^ (rA & 7)) << 3));
        acc[0][mt] = __builtin_amdgcn_mfma_f32_16x16x32_bf16(a, Bf[0][ks], acc[0][mt], 0, 0, 0);
        acc[1][mt] = __builtin_amdgcn_mfma_f32_16x16x32_bf16(a, Bf[1][ks], acc[1][mt], 0, 0, 0);
      }
    }
#pragma unroll
    for (int set = 0; set < 2; ++set)
#pragma unroll
      for (int mt = 0; mt < 4; ++mt)
#pragma unroll
        for (int j = 0; j < 4; ++j) {
          const int ml = mt * 16 + fq * 4 + j;
          const int mm = m_base + ml;
          if (mm < M_TOT) ins4_nd(acc[set][mt][j] * wscaleL[ml], mm, ts[set], ti[set]);
        }
    __syncthreads();
  }

#pragma unroll
  for (int mask = 16; mask < 64; mask <<= 1) {
#pragma unroll
    for (int set = 0; set < 2; ++set) {
      float os[4]; int oi[4];
#pragma unroll
      for (int q = 0; q < 4; ++q) {
        os[q] = __shfl_xor(ts[set][q], mask);
        oi[q] = __shfl_xor(ti[set][q], mask);
      }
#pragma unroll
      for (int q = 0; q < 4; ++q) ins4(os[q], oi[q], ts[set], ti[set]);
    }
  }
  if (fq == 0) {
#pragma unroll
    for (int set = 0; set < 2; ++set) {
      const int b = set * 64 + w * 16 + fr;
      const size_t base = ((size_t)b * NCHUNK + blockIdx.x) * 4;
#pragma unroll
      for (int q = 0; q < 4; ++q) { cand_s[base + q] = ts[set][q]; cand_i[base + q] = ti[set][q]; }
    }
  }
}

// ---------------------------------------------------------------- merge + rescore + fuse + policy heads (fused)
__global__ __launch_bounds__(256)
void topk_heads(const float* __restrict__ cand_s, const int* __restrict__ cand_i,
                const float* __restrict__ bank, const float* __restrict__ vals,
                const float* __restrict__ rnorm, const float* __restrict__ r0,
                const float* __restrict__ Wc, const float* __restrict__ bc,
                const float* __restrict__ Wd, const float* __restrict__ bd,
                const float* __restrict__ Wsw, const float* __restrict__ bsw,
                const float* __restrict__ Wv, const float* __restrict__ bv,
                float* __restrict__ out) {
  const int b = blockIdx.x, t = threadIdx.x;
  __shared__ float rnL[256];
  __shared__ float ss[2048];
  __shared__ int   si[2048];
  __shared__ int   g8[8];
  __shared__ float sc8[8];
  __shared__ int   gidx[3];
  __shared__ float rl[256];
  __shared__ float red[256];
  __shared__ float hd[8];

  rnL[t] = rnorm[b * 256 + t];

  float ts[8]; int ti[8];
#pragma unroll
  for (int q = 0; q < 8; ++q) { ts[q] = -INFINITY; ti[q] = 0x7fffff00 + t * 8 + q; }
  const int n = NCHUNK * 4;
  const size_t base = (size_t)b * n;
  for (int c = t; c < n; c += 256) ins8(cand_s[base + c], cand_i[base + c], ts, ti);
#pragma unroll
  for (int q = 0; q < 8; ++q) { ss[t * 8 + q] = ts[q]; si[t * 8 + q] = ti[q]; }
  __syncthreads();

  if (t < 64) {
    float ms[8]; int mi[8];
#pragma unroll
    for (int q = 0; q < 8; ++q) { ms[q] = -INFINITY; mi[q] = 0x7ffffe00 + t * 8 + q; }
    for (int c = t * 32; c < t * 32 + 32; ++c) ins8(ss[c], si[c], ms, mi);
#pragma unroll
    for (int mask = 1; mask < 64; mask <<= 1) {
      float os[8]; int oi[8];
#pragma unroll
      for (int q = 0; q < 8; ++q) { os[q] = __shfl_xor(ms[q], mask); oi[q] = __shfl_xor(mi[q], mask); }
#pragma unroll
      for (int q = 0; q < 8; ++q) ins8(os[q], oi[q], ms, mi);
    }
    if (t == 0) {
#pragma unroll
      for (int q = 0; q < 8; ++q) g8[q] = mi[q];
    }
  }
  __syncthreads();

  {
    const int c = t >> 5, g = t & 31;
    const int id = g8[c];
    float ssq = 0.0f, dt = 0.0f;
    if (id < M_TOT) {
      const float4* bp = reinterpret_cast<const float4*>(bank + (size_t)id * 256);
      const float4 x0 = bp[g * 2], x1 = bp[g * 2 + 1];
      const float4 r0v = *reinterpret_cast<const float4*>(&rnL[g * 8]);
      const float4 r1v = *reinterpret_cast<const float4*>(&rnL[g * 8 + 4]);
      ssq = x0.x*x0.x + x0.y*x0.y + x0.z*x0.z + x0.w*x0.w +
            x1.x*x1.x + x1.y*x1.y + x1.z*x1.z + x1.w*x1.w;
      dt  = x0.x*r0v.x + x0.y*r0v.y + x0.z*r0v.z + x0.w*r0v.w +
            x1.x*r1v.x + x1.y*r1v.y + x1.z*r1v.z + x1.w*r1v.w;
    }
#pragma unroll
    for (int mask = 1; mask < 32; mask <<= 1) { ssq += __shfl_xor(ssq, mask); dt += __shfl_xor(dt, mask); }
    if (g == 0)
      sc8[c] = (id < M_TOT)
                 ? dt * (1.0f / fmaxf(sqrtf(ssq), 1e-12f)) * (vals[id] + 1e-8f)
                 : -INFINITY;
  }
  __syncthreads();

  if (t == 0) {
    float gs[3] = {-INFINITY, -INFINITY, -INFINITY};
    int gi[3] = {0x7fffffff, 0x7ffffffe, 0x7ffffffd};
#pragma unroll
    for (int q = 0; q < 8; ++q) ins3(sc8[q], g8[q], gs, gi);
    gidx[0] = gi[0]; gidx[1] = gi[1]; gidx[2] = gi[2];
  }
  __syncthreads();

  {
    const int i0 = gidx[0], i1 = gidx[1], i2 = gidx[2];
    const float retr = (bank[(size_t)i0 * 256 + t] + bank[(size_t)i1 * 256 + t] +
                        bank[(size_t)i2 * 256 + t]) / 3.0f;
    rl[t] = 0.5f * r0[b * 256 + t] + 0.5f * retr;
  }
  __syncthreads();

  float y = bd[t];
#pragma unroll 8
  for (int k = 0; k < 256; ++k) y += rl[k] * Wd[k * 256 + t];
  red[t] = y * y;
  if (t < 4) {
    float a;
    if (t == 0) { a = bc[0]; for (int k = 0; k < 256; ++k) a += rl[k] * Wc[2 * k]; }
    else if (t == 1) { a = bc[1]; for (int k = 0; k < 256; ++k) a += rl[k] * Wc[2 * k + 1]; }
    else if (t == 2) { a = bsw[0]; for (int k = 0; k < 256; ++k) a += rl[k] * Wsw[k]; }
    else { a = bv[0]; for (int k = 0; k < 256; ++k) a += rl[k] * Wv[k]; }
    hd[t] = a;
  }
  __syncthreads();
  for (int s = 128; s > 0; s >>= 1) { if (t < s) red[t] += red[t + s]; __syncthreads(); }
  const float dirn = y / fmaxf(sqrtf(red[0]), 1e-12f);
  if (t == 0) {
    const float l0 = hd[0], l1 = hd[1];
    uint32_t a0, a1, c0, c1;
    threefry2x32(0u, 1u, 0u, (uint32_t)(2 * b), a0, a1);
    threefry2x32(0u, 1u, 0u, (uint32_t)(2 * b + 1), c0, c1);
    const float g0 = gumbel_from_bits(a0 ^ a1);
    const float g1 = gumbel_from_bits(c0 ^ c1);
    const int act = (l1 + g1 > l0 + g0) ? 1 : 0;
    const float mx = fmaxf(l0, l1);
    const float lse = mx + logf(expf(l0 - mx) + expf(l1 - mx));
    const float lp0 = l0 - lse, lp1 = l1 - lse;
    out[OFF_ACT + b] = (float)act;
    out[OFF_LP + b] = act ? lp1 : lp0;
    out[OFF_VAL + b] = hd[3];
    out[OFF_ENT + b] = -(expf(lp0) * lp0 + expf(lp1) * lp1);
    hd[4] = 2.0f / (1.0f + expf(-hd[2]));
  }
  __syncthreads();
  out[OFF_POS + b * 256 + t] = rl[t] + hd[4] * dirn;
}

// ---------------------------------------------------------------- launch
extern "C" void kernel_launch(void* const* d_in, const int* in_sizes, int n_in,
                              void* d_out, int out_size, void* d_ws, size_t ws_size,
                              hipStream_t stream) {
  const float* state = (const float*)d_in[0];
  const float* bank  = (const float*)d_in[1];
  const float* vals  = (const float*)d_in[2];
  const float* W1  = (const float*)d_in[3];
  const float* b1  = (const float*)d_in[4];
  const float* W2  = (const float*)d_in[5];
  const float* b2  = (const float*)d_in[6];
  const float* Wc  = (const float*)d_in[7];
  const float* bc  = (const float*)d_in[8];
  const float* Wd  = (const float*)d_in[9];
  const float* bd  = (const float*)d_in[10];
  const float* Wsw = (const float*)d_in[11];
  const float* bsw = (const float*)d_in[12];
  const float* Wv  = (const float*)d_in[13];
  const float* bv  = (const float*)d_in[14];
  const float* T1w = (const float*)d_in[15];
  const float* t1b = (const float*)d_in[16];
  const float* T2w = (const float*)d_in[17];
  const float* t2b = (const float*)d_in[18];
  float* out = (float*)d_out;
  float* ws = (float*)d_ws;

  // base workspace layout (floats); regA overlaps cs/ci (regA dead between
  // combine_h1 consumption and any later use -- T2 now writes out directly).
  float* regA = ws;                   // 1,048,576 (W1 partials 8x131072)
  float* cs   = ws;                   // 250,368 (128*489*4)  [overlaps regA]
  int*   ci   = (int*)(ws + 250368);  // 250,368              [overlaps regA]
  float* h1   = ws + 1048576;         // 131072
  float* regC = ws + 1179648;         // 262144 (W2 partials 8x32768)
  float* r0   = ws + 1441792;         // 32768
  float* rnm  = ws + 1474560;         // 32768
  float* h2   = ws + 1507328;         // 131072  -> base end 1,638,400

  // path-A extras
  uint32_t* rnbf   = (uint32_t*)(ws + 1638400);   // 16,384 u32
  uint32_t* bankbf = (uint32_t*)(ws + 1654784);   // NPAD*128 = 64,094,208 u32
  const size_t NEED_BYTES = (size_t)(1654784 + (size_t)NPAD * 128) * 4;  // ~263 MB
  const bool pathA = ws_size >= NEED_BYTES;

  // state_projection: H -> H/4 (relu) -> R
  gemm_tile<0><<<dim3(16, 2, 8), 256, 0, stream>>>(state, W1, nullptr, regA, 128, 1024, 4096, 512);
  combine_z<8, true><<<512, 256, 0, stream>>>(regA, b1, h1, 131072, 1023);
  gemm_tile<0><<<dim3(4, 2, 8), 256, 0, stream>>>(h1, W2, nullptr, regC, 128, 256, 1024, 128);
  combine_r0<<<128, 256, 0, stream>>>(regC, b2, r0, rnm, pathA ? rnbf : nullptr);
  // retrieval
  if (pathA) {
    prep_bank<<<2048, 256, 0, stream>>>(bank, vals, bankbf);
    sims_topk_a<<<NCHUNK, 512, 0, stream>>>(rnbf, bankbf, cs, ci);
  } else {
    sims_topk_b<<<NCHUNK, 256, 0, stream>>>(rnm, bank, vals, cs, ci);
  }
  topk_heads<<<128, 256, 0, stream>>>(cs, ci, bank, vals, rnm, r0,
                                      Wc, bc, Wd, bd, Wsw, bsw, Wv, bv, out);
  // thought_projection: R -> H/4 (relu) -> H (direct bias epilogues)
  gemm_tile<2><<<dim3(16, 2, 1), 256, 0, stream>>>(out + OFF_POS, T1w, t1b, h2, 128, 1024, 256, 256);
  gemm_tile<1><<<dim3(64, 2, 1), 256, 0, stream>>>(h2, T2w, t2b, out + OFF_LATENT, 128, 4096, 1024, 1024);
}

// Round 16
// 450.100 us; speedup vs baseline: 1.1187x; 1.1187x over previous
//
#include <hip/hip_runtime.h>
#include <hip/hip_bf16.h>
#include <math.h>
#include <stdint.h>

// Problem constants (CoconutPPO): B=128, H=4096, R=256, M=500000, K=3
#define BB 128
#define HH 4096
#define RR 256
#define M_TOT 500000
#define CHUNK 1024
#define NCHUNK ((M_TOT + CHUNK - 1) / CHUNK)   // 489
#define NPAD (NCHUNK * CHUNK)                  // 500736
#define TINYF 1.17549435e-38f

// d_out layout (floats, concatenated in return order)
#define OFF_LATENT 0
#define OFF_POS    524288
#define OFF_ACT    557056
#define OFF_LP     557184
#define OFF_VAL    557312
#define OFF_ENT    557440

typedef __attribute__((ext_vector_type(8))) short bf16x8;
typedef __attribute__((ext_vector_type(4))) float f32x4;

// ---------------------------------------------------------------- helpers
__device__ __forceinline__ bool better(float a, int ia, float b, int ib) {
  return a > b || (a == b && ia < ib);
}
__device__ __forceinline__ void ins4_nd(float s, int id, float (&vs)[4], int (&vi)[4]) {
  if (better(s, id, vs[3], vi[3])) {
    vs[3] = s; vi[3] = id;
    if (better(vs[3], vi[3], vs[2], vi[2])) { float a=vs[3]; vs[3]=vs[2]; vs[2]=a; int x=vi[3]; vi[3]=vi[2]; vi[2]=x; }
    if (better(vs[2], vi[2], vs[1], vi[1])) { float a=vs[2]; vs[2]=vs[1]; vs[1]=a; int x=vi[2]; vi[2]=vi[1]; vi[1]=x; }
    if (better(vs[1], vi[1], vs[0], vi[0])) { float a=vs[1]; vs[1]=vs[0]; vs[0]=a; int x=vi[1]; vi[1]=vi[0]; vi[0]=x; }
  }
}
__device__ __forceinline__ void ins4(float s, int id, float (&vs)[4], int (&vi)[4]) {
  if (id == vi[0] || id == vi[1] || id == vi[2] || id == vi[3]) return;
  ins4_nd(s, id, vs, vi);
}
__device__ __forceinline__ void ins3(float s, int id, float (&vs)[3], int (&vi)[3]) {
  if (id == vi[0] || id == vi[1] || id == vi[2]) return;
  if (better(s, id, vs[2], vi[2])) {
    vs[2] = s; vi[2] = id;
    if (better(vs[2], vi[2], vs[1], vi[1])) { float a=vs[2]; vs[2]=vs[1]; vs[1]=a; int x=vi[2]; vi[2]=vi[1]; vi[1]=x; }
    if (better(vs[1], vi[1], vs[0], vi[0])) { float a=vs[1]; vs[1]=vs[0]; vs[0]=a; int x=vi[1]; vi[1]=vi[0]; vi[0]=x; }
  }
}
__device__ __forceinline__ void ins8(float s, int id, float (&vs)[8], int (&vi)[8]) {
#pragma unroll
  for (int q = 0; q < 8; ++q) if (id == vi[q]) return;
  if (!better(s, id, vs[7], vi[7])) return;
  vs[7] = s; vi[7] = id;
#pragma unroll
  for (int q = 7; q > 0; --q)
    if (better(vs[q], vi[q], vs[q-1], vi[q-1])) {
      float a = vs[q]; vs[q] = vs[q-1]; vs[q-1] = a;
      int x = vi[q]; vi[q] = vi[q-1]; vi[q-1] = x;
    }
}

// RNE f32 -> bf16 (bit arithmetic; matches hardware/NumPy RNE)
__device__ __forceinline__ uint32_t rne_u(float x) {
  uint32_t u = __float_as_uint(x);
  return (u + 0x7fffu + ((u >> 16) & 1u)) >> 16;
}
__device__ __forceinline__ uint32_t pk_bf16(float lo, float hi) {
  return rne_u(lo) | (rne_u(hi) << 16);
}

// async global->LDS (wave-uniform LDS base, per-lane global source)
__device__ __forceinline__ void load_lds16(const void* g, void* l) {
  __builtin_amdgcn_global_load_lds((const __attribute__((address_space(1))) void*)g,
                                   (__attribute__((address_space(3))) void*)l, 16, 0, 0);
}

#define TF_ROUND(r) { x0 += x1; x1 = (x1 << (r)) | (x1 >> (32 - (r))); x1 ^= x0; }
__device__ __forceinline__ void threefry2x32(uint32_t k0, uint32_t k1,
                                             uint32_t x0, uint32_t x1,
                                             uint32_t& o0, uint32_t& o1) {
  const uint32_t ks2 = k0 ^ k1 ^ 0x1BD11BDAu;
  x0 += k0; x1 += k1;
  TF_ROUND(13) TF_ROUND(15) TF_ROUND(26) TF_ROUND(6)
  x0 += k1; x1 += ks2 + 1u;
  TF_ROUND(17) TF_ROUND(29) TF_ROUND(16) TF_ROUND(24)
  x0 += ks2; x1 += k0 + 2u;
  TF_ROUND(13) TF_ROUND(15) TF_ROUND(26) TF_ROUND(6)
  x0 += k0; x1 += k1 + 3u;
  TF_ROUND(17) TF_ROUND(29) TF_ROUND(16) TF_ROUND(24)
  x0 += k1; x1 += ks2 + 4u;
  TF_ROUND(13) TF_ROUND(15) TF_ROUND(26) TF_ROUND(6)
  x0 += ks2; x1 += k0 + 5u;
  o0 = x0; o1 = x1;
}

__device__ __forceinline__ float gumbel_from_bits(uint32_t bits) {
  const uint32_t fb = (bits >> 9) | 0x3f800000u;
  const float fl = __uint_as_float(fb) - 1.0f;
  const float u = fmaxf(TINYF, fl * (1.0f - TINYF) + TINYF);
  return -logf(-logf(u));
}

// ---------------------------------------------------------------- generic fp32 GEMM (partial slabs)
__global__ __launch_bounds__(256)
void gemm_tile(const float* __restrict__ A, const float* __restrict__ Bw,
               float* __restrict__ C, int Mr, int Nc, int K, int klen) {
  __shared__ float As[16][68];
  __shared__ float Bs[16][68];
  const int col0 = blockIdx.x * 64;
  const int row0 = blockIdx.y * 64;
  const int k0 = blockIdx.z * klen;
  const int t = threadIdx.x;
  const int tc = t & 15, tr = t >> 4;
  float acc[4][4] = {};
  for (int kk = k0; kk < k0 + klen; kk += 16) {
    {
      const int r = t >> 2, c4 = (t & 3) << 2;
      const float4 v = *reinterpret_cast<const float4*>(A + (size_t)(row0 + r) * K + kk + c4);
      As[c4 + 0][r] = v.x; As[c4 + 1][r] = v.y; As[c4 + 2][r] = v.z; As[c4 + 3][r] = v.w;
    }
    {
      const int kr = t >> 4, c4 = (t & 15) << 2;
      const float4 v = *reinterpret_cast<const float4*>(Bw + (size_t)(kk + kr) * Nc + col0 + c4);
      *reinterpret_cast<float4*>(&Bs[kr][c4]) = v;
    }
    __syncthreads();
#pragma unroll
    for (int k = 0; k < 16; ++k) {
      const float4 a4 = *reinterpret_cast<const float4*>(&As[k][tr * 4]);
      const float4 b4 = *reinterpret_cast<const float4*>(&Bs[k][tc * 4]);
      float a[4] = {a4.x, a4.y, a4.z, a4.w};
      float b[4] = {b4.x, b4.y, b4.z, b4.w};
#pragma unroll
      for (int i = 0; i < 4; ++i)
#pragma unroll
        for (int j = 0; j < 4; ++j) acc[i][j] += a[i] * b[j];
    }
    __syncthreads();
  }
  float* Cp = C + (size_t)blockIdx.z * Mr * Nc;
#pragma unroll
  for (int i = 0; i < 4; ++i) {
    const int row = row0 + tr * 4 + i;
#pragma unroll
    for (int j = 0; j < 4; ++j) {
      Cp[(size_t)row * Nc + col0 + tc * 4 + j] = acc[i][j];
    }
  }
}

// ---------------------------------------------------------------- combines
template<int Z, bool RELU>
__global__ void combine_z(const float* __restrict__ src, const float* __restrict__ bias,
                          float* __restrict__ dst, int total, int mask) {
  const int i = blockIdx.x * 256 + threadIdx.x;
  float v = bias[i & mask];
#pragma unroll
  for (int z = 0; z < Z; ++z) v += src[(size_t)z * total + i];
  dst[i] = RELU ? fmaxf(v, 0.0f) : v;
}

__global__ __launch_bounds__(256)
void combine_r0(const float* __restrict__ r0p, const float* __restrict__ b2,
                float* __restrict__ r0, float* __restrict__ rnorm,
                uint32_t* __restrict__ rnbf) {
  const int b = blockIdx.x, t = threadIdx.x;
  __shared__ float red[256];
  __shared__ float vtmp[256];
  float v = b2[t];
#pragma unroll
  for (int z = 0; z < 8; ++z) v += r0p[z * 32768 + b * 256 + t];
  r0[b * 256 + t] = v;
  red[t] = v * v;
  __syncthreads();
  for (int s = 128; s > 0; s >>= 1) { if (t < s) red[t] += red[t + s]; __syncthreads(); }
  const float inv = 1.0f / fmaxf(sqrtf(red[0]), 1e-12f);
  const float vn = v * inv;
  rnorm[b * 256 + t] = vn;
  if (rnbf) {
    vtmp[t] = vn;
    __syncthreads();
    if (t < 128) rnbf[b * 128 + t] = pk_bf16(vtmp[2 * t], vtmp[2 * t + 1]);
  }
}

// ---------------------------------------------------------------- prep pass (path A)
__global__ __launch_bounds__(256)
void prep_bank(const float* __restrict__ bank, const float* __restrict__ vals,
               uint32_t* __restrict__ bankbf) {
  const int lane = threadIdx.x & 63;
  const int wid = blockIdx.x * 4 + (threadIdx.x >> 6);
  const int nw = gridDim.x * 4;
  for (int m = wid; m < NPAD; m += nw) {
    float4 v = make_float4(0.f, 0.f, 0.f, 0.f);
    float vv = 0.0f;
    if (m < M_TOT) {
      v = *reinterpret_cast<const float4*>(bank + (size_t)m * 256 + lane * 4);
      vv = vals[m];                       // wave-uniform address -> 1 transaction
    }
    float s = v.x * v.x + v.y * v.y + v.z * v.z + v.w * v.w;
#pragma unroll
    for (int msk = 1; msk < 64; msk <<= 1) s += __shfl_xor(s, msk);
    const float wsc = (vv + 1e-8f) / fmaxf(sqrtf(s), 1e-12f);
    uint2 p;
    p.x = pk_bf16(v.x * wsc, v.y * wsc);
    p.y = pk_bf16(v.z * wsc, v.w * wsc);
    const int c = lane >> 1;
    *reinterpret_cast<uint2*>(
        reinterpret_cast<char*>(bankbf) + (size_t)m * 512 +
        (((c ^ (m & 7)) << 4) + (lane & 1) * 8)) = p;
  }
}

// ---------------------------------------------------------------- MFMA sims (path A)
// 512 thr / 8 waves, 64 KB LDS (4 bufs x 32 rows) -> 2 blocks/CU, 489 blocks
// = one balanced scheduling wave. 32 subs of 32 rows; 3-deep counted-vmcnt
// pipeline (never drain vmcnt to 0 mid-loop). One 16-row batch set per wave.
__global__ __launch_bounds__(512, 4)
void sims_topk_a(const uint32_t* __restrict__ rnbf, const uint32_t* __restrict__ bankbf,
                 float* __restrict__ cand_s, int* __restrict__ cand_i) {
  __shared__ __align__(16) unsigned short tA[4][32 * 256];   // 4 x 16 KB

  const int t = threadIdx.x;
  const int lane = t & 63;
  const int w = t >> 6;            // wave 0..7 -> batch rows w*16..w*16+15
  const int fr = lane & 15;
  const int fq = lane >> 4;        // 0..3 (k-group)

  // ---- B-frags (one batch set per wave) from bf16 rnorm (row-major packed)
  bf16x8 Bf[8];
  {
    const uint4* rp = reinterpret_cast<const uint4*>(rnbf + (size_t)(w * 16 + fr) * 128);
#pragma unroll
    for (int ks = 0; ks < 8; ++ks) {
      uint4 u = rp[ks * 4 + fq];
      Bf[ks] = *reinterpret_cast<bf16x8*>(&u);
    }
  }

  float ts[4]; int ti[4];
#pragma unroll
  for (int q = 0; q < 4; ++q) { ts[q] = -INFINITY; ti[q] = 0x7ffffff0 + q; }

  const char* bb = reinterpret_cast<const char*>(bankbf);

  // issue one sub's staging (2 x 1KB per wave; row-pairs p = w*2+i)
  auto issue = [&](int sub) {
    const int mb = blockIdx.x * CHUNK + sub * 32;
    const int buf = sub & 3;
#pragma unroll
    for (int i = 0; i < 2; ++i) {
      const int p = w * 2 + i;     // row-pair 0..15 (2 rows x 512B)
      load_lds16(bb + (size_t)(mb + p * 2) * 512 + lane * 16,
                 reinterpret_cast<char*>(tA[buf]) + p * 1024);
    }
  };

  issue(0); issue(1); issue(2);
  asm volatile("s_waitcnt vmcnt(4)" ::: "memory");   // sub 0 landed
  __builtin_amdgcn_s_barrier();

  for (int sub = 0; sub < 32; ++sub) {
    if (sub + 3 < 32) issue(sub + 3);
    const int m_base = blockIdx.x * CHUNK + sub * 32;
    const unsigned short* tc = tA[sub & 3];

    // ---- MFMA: 32 mem rows x 16 batch rows (this wave's set)
    f32x4 acc[2];
#pragma unroll
    for (int mt = 0; mt < 2; ++mt) acc[mt] = (f32x4){0.f, 0.f, 0.f, 0.f};
#pragma unroll
    for (int ks = 0; ks < 8; ++ks) {
      const int kc = ks * 4 + fq;
#pragma unroll
      for (int mt = 0; mt < 2; ++mt) {
        const int rA = mt * 16 + fr;
        const bf16x8 a = *reinterpret_cast<const bf16x8*>(
            tc + rA * 256 + ((kc ^ (rA & 7)) << 3));
        acc[mt] = __builtin_amdgcn_mfma_f32_16x16x32_bf16(a, Bf[ks], acc[mt], 0, 0, 0);
      }
    }
    // ---- epilogue: prescaled scores -> per-lane top-4
#pragma unroll
    for (int mt = 0; mt < 2; ++mt)
#pragma unroll
      for (int j = 0; j < 4; ++j) {
        const int ml = mt * 16 + fq * 4 + j;
        const int mm = m_base + ml;
        if (mm < M_TOT) ins4_nd(acc[mt][j], mm, ts, ti);
      }

    // ---- counted wait: only require sub+1 landed; keep newer loads in flight
    if (sub < 29) {
      asm volatile("s_waitcnt vmcnt(4)" ::: "memory");
      __builtin_amdgcn_s_barrier();
    } else if (sub == 29) {
      asm volatile("s_waitcnt vmcnt(2)" ::: "memory");
      __builtin_amdgcn_s_barrier();
    } else if (sub == 30) {
      asm volatile("s_waitcnt vmcnt(0)" ::: "memory");
      __builtin_amdgcn_s_barrier();
    }
  }

  // merge the 4 fq-lane groups sharing each batch row (snapshot butterfly)
#pragma unroll
  for (int mask = 16; mask < 64; mask <<= 1) {
    float os[4]; int oi[4];
#pragma unroll
    for (int q = 0; q < 4; ++q) {
      os[q] = __shfl_xor(ts[q], mask);
      oi[q] = __shfl_xor(ti[q], mask);
    }
#pragma unroll
    for (int q = 0; q < 4; ++q) ins4(os[q], oi[q], ts, ti);
  }
  if (fq == 0) {
    const int b = w * 16 + fr;
    const size_t base = ((size_t)b * NCHUNK + blockIdx.x) * 4;
#pragma unroll
    for (int q = 0; q < 4; ++q) { cand_s[base + q] = ts[q]; cand_i[base + q] = ti[q]; }
  }
}

// ---------------------------------------------------------------- MFMA sims (path B fallback, fp32 single pass)
__global__ __launch_bounds__(256, 4)
void sims_topk_b(const float* __restrict__ rnorm, const float* __restrict__ bank,
                 const float* __restrict__ vals, float* __restrict__ cand_s,
                 int* __restrict__ cand_i) {
  __shared__ __align__(16) unsigned short tA[64 * 256];
  __shared__ float wscaleL[64];

  const int t = threadIdx.x;
  const int lane = t & 63;
  const int w = t >> 6;
  const int fr = lane & 15;
  const int fq = lane >> 4;

  bf16x8 Bf[2][8];
#pragma unroll
  for (int set = 0; set < 2; ++set) {
    const float* rp = rnorm + (size_t)(set * 64 + w * 16 + fr) * 256 + fq * 8;
#pragma unroll
    for (int ks = 0; ks < 8; ++ks) {
      const float4 x0 = *reinterpret_cast<const float4*>(rp + ks * 32);
      const float4 x1 = *reinterpret_cast<const float4*>(rp + ks * 32 + 4);
      uint4 pk;
      pk.x = pk_bf16(x0.x, x0.y);
      pk.y = pk_bf16(x0.z, x0.w);
      pk.z = pk_bf16(x1.x, x1.y);
      pk.w = pk_bf16(x1.z, x1.w);
      Bf[set][ks] = *reinterpret_cast<bf16x8*>(&pk);
    }
  }

  float ts[2][4]; int ti[2][4];
#pragma unroll
  for (int set = 0; set < 2; ++set)
#pragma unroll
    for (int q = 0; q < 4; ++q) { ts[set][q] = -INFINITY; ti[set][q] = 0x7ffffff0 + q; }

  for (int sub = 0; sub < 16; ++sub) {
    const int m_base = blockIdx.x * CHUNK + sub * 64;
#pragma unroll 4
    for (int i = 0; i < 16; ++i) {
      const int r = i * 4 + w;
      const int m = m_base + r;
      float4 v = make_float4(0.f, 0.f, 0.f, 0.f);
      if (m < M_TOT)
        v = *reinterpret_cast<const float4*>(bank + (size_t)m * 256 + lane * 4);
      float s = v.x * v.x + v.y * v.y + v.z * v.z + v.w * v.w;
#pragma unroll
      for (int msk = 1; msk < 64; msk <<= 1) s += __shfl_xor(s, msk);
      const uint32_t p0 = pk_bf16(v.x, v.y);
      const uint32_t p1 = pk_bf16(v.z, v.w);
      const int cc = lane >> 1, h = lane & 1;
      uint32_t* dst = reinterpret_cast<uint32_t*>(
          tA + (size_t)r * 256 + (((cc ^ (r & 7)) << 3) + h * 4));
      dst[0] = p0; dst[1] = p1;
      if (lane == 0) {
        const float vv = (m < M_TOT) ? vals[m] : 0.0f;
        wscaleL[r] = (vv + 1e-8f) / fmaxf(sqrtf(s), 1e-12f);
      }
    }
    __syncthreads();

    f32x4 acc[2][4];
#pragma unroll
    for (int set = 0; set < 2; ++set)
#pragma unroll
      for (int mt = 0; mt < 4; ++mt) acc[set][mt] = (f32x4){0.f, 0.f, 0.f, 0.f};
#pragma unroll
    for (int ks = 0; ks < 8; ++ks) {
      const int kc = ks * 4 + fq;
#pragma unroll
      for (int mt = 0; mt < 4; ++mt) {
        const int rA = mt * 16 + fr;
        const bf16x8 a = *reinterpret_cast<const bf16x8*>(tA + rA * 256 + ((kc ^ (rA & 7)) << 3));
        acc[0][mt] = __builtin_amdgcn_mfma_f32_16x16x32_bf16(a, Bf[0][ks], acc[0][mt], 0, 0, 0);
        acc[1][mt] = __builtin_amdgcn_mfma_f32_16x16x32_bf16(a, Bf[1][ks], acc[1][mt], 0, 0, 0);
      }
    }
#pragma unroll
    for (int set = 0; set < 2; ++set)
#pragma unroll
      for (int mt = 0; mt < 4; ++mt)
#pragma unroll
        for (int j = 0; j < 4; ++j) {
          const int ml = mt * 16 + fq * 4 + j;
          const int mm = m_base + ml;
          if (mm < M_TOT) ins4_nd(acc[set][mt][j] * wscaleL[ml], mm, ts[set], ti[set]);
        }
    __syncthreads();
  }

#pragma unroll
  for (int mask = 16; mask < 64; mask <<= 1) {
#pragma unroll
    for (int set = 0; set < 2; ++set) {
      float os[4]; int oi[4];
#pragma unroll
      for (int q = 0; q < 4; ++q) {
        os[q] = __shfl_xor(ts[set][q], mask);
        oi[q] = __shfl_xor(ti[set][q], mask);
      }
#pragma unroll
      for (int q = 0; q < 4; ++q) ins4(os[q], oi[q], ts[set], ti[set]);
    }
  }
  if (fq == 0) {
#pragma unroll
    for (int set = 0; set < 2; ++set) {
      const int b = set * 64 + w * 16 + fr;
      const size_t base = ((size_t)b * NCHUNK + blockIdx.x) * 4;
#pragma unroll
      for (int q = 0; q < 4; ++q) { cand_s[base + q] = ts[set][q]; cand_i[base + q] = ti[set][q]; }
    }
  }
}

// ---------------------------------------------------------------- merge + rescore + fuse + policy heads (fused)
__global__ __launch_bounds__(256)
void topk_heads(const float* __restrict__ cand_s, const int* __restrict__ cand_i,
                const float* __restrict__ bank, const float* __restrict__ vals,
                const float* __restrict__ rnorm, const float* __restrict__ r0,
                const float* __restrict__ Wc, const float* __restrict__ bc,
                const float* __restrict__ Wd, const float* __restrict__ bd,
                const float* __restrict__ Wsw, const float* __restrict__ bsw,
                const float* __restrict__ Wv, const float* __restrict__ bv,
                float* __restrict__ out) {
  const int b = blockIdx.x, t = threadIdx.x;
  __shared__ float rnL[256];
  __shared__ float ss[2048];
  __shared__ int   si[2048];
  __shared__ int   g8[8];
  __shared__ float sc8[8];
  __shared__ int   gidx[3];
  __shared__ float rl[256];
  __shared__ float red[256];
  __shared__ float hd[8];

  rnL[t] = rnorm[b * 256 + t];

  float ts[8]; int ti[8];
#pragma unroll
  for (int q = 0; q < 8; ++q) { ts[q] = -INFINITY; ti[q] = 0x7fffff00 + t * 8 + q; }
  const int n = NCHUNK * 4;
  const size_t base = (size_t)b * n;
  for (int c = t; c < n; c += 256) ins8(cand_s[base + c], cand_i[base + c], ts, ti);
#pragma unroll
  for (int q = 0; q < 8; ++q) { ss[t * 8 + q] = ts[q]; si[t * 8 + q] = ti[q]; }
  __syncthreads();

  if (t < 64) {
    float ms[8]; int mi[8];
#pragma unroll
    for (int q = 0; q < 8; ++q) { ms[q] = -INFINITY; mi[q] = 0x7ffffe00 + t * 8 + q; }
    for (int c = t * 32; c < t * 32 + 32; ++c) ins8(ss[c], si[c], ms, mi);
#pragma unroll
    for (int mask = 1; mask < 64; mask <<= 1) {
      float os[8]; int oi[8];
#pragma unroll
      for (int q = 0; q < 8; ++q) { os[q] = __shfl_xor(ms[q], mask); oi[q] = __shfl_xor(mi[q], mask); }
#pragma unroll
      for (int q = 0; q < 8; ++q) ins8(os[q], oi[q], ms, mi);
    }
    if (t == 0) {
#pragma unroll
      for (int q = 0; q < 8; ++q) g8[q] = mi[q];
    }
  }
  __syncthreads();

  {
    const int c = t >> 5, g = t & 31;
    const int id = g8[c];
    float ssq = 0.0f, dt = 0.0f;
    if (id < M_TOT) {
      const float4* bp = reinterpret_cast<const float4*>(bank + (size_t)id * 256);
      const float4 x0 = bp[g * 2], x1 = bp[g * 2 + 1];
      const float4 r0v = *reinterpret_cast<const float4*>(&rnL[g * 8]);
      const float4 r1v = *reinterpret_cast<const float4*>(&rnL[g * 8 + 4]);
      ssq = x0.x*x0.x + x0.y*x0.y + x0.z*x0.z + x0.w*x0.w +
            x1.x*x1.x + x1.y*x1.y + x1.z*x1.z + x1.w*x1.w;
      dt  = x0.x*r0v.x + x0.y*r0v.y + x0.z*r0v.z + x0.w*r0v.w +
            x1.x*r1v.x + x1.y*r1v.y + x1.z*r1v.z + x1.w*r1v.w;
    }
#pragma unroll
    for (int mask = 1; mask < 32; mask <<= 1) { ssq += __shfl_xor(ssq, mask); dt += __shfl_xor(dt, mask); }
    if (g == 0)
      sc8[c] = (id < M_TOT)
                 ? dt * (1.0f / fmaxf(sqrtf(ssq), 1e-12f)) * (vals[id] + 1e-8f)
                 : -INFINITY;
  }
  __syncthreads();

  if (t == 0) {
    float gs[3] = {-INFINITY, -INFINITY, -INFINITY};
    int gi[3] = {0x7fffffff, 0x7ffffffe, 0x7ffffffd};
#pragma unroll
    for (int q = 0; q < 8; ++q) ins3(sc8[q], g8[q], gs, gi);
    gidx[0] = gi[0]; gidx[1] = gi[1]; gidx[2] = gi[2];
  }
  __syncthreads();

  {
    const int i0 = gidx[0], i1 = gidx[1], i2 = gidx[2];
    const float retr = (bank[(size_t)i0 * 256 + t] + bank[(size_t)i1 * 256 + t] +
                        bank[(size_t)i2 * 256 + t]) / 3.0f;
    rl[t] = 0.5f * r0[b * 256 + t] + 0.5f * retr;
  }
  __syncthreads();

  float y = bd[t];
#pragma unroll 8
  for (int k = 0; k < 256; ++k) y += rl[k] * Wd[k * 256 + t];
  red[t] = y * y;
  if (t < 4) {
    float a;
    if (t == 0) { a = bc[0]; for (int k = 0; k < 256; ++k) a += rl[k] * Wc[2 * k]; }
    else if (t == 1) { a = bc[1]; for (int k = 0; k < 256; ++k) a += rl[k] * Wc[2 * k + 1]; }
    else if (t == 2) { a = bsw[0]; for (int k = 0; k < 256; ++k) a += rl[k] * Wsw[k]; }
    else { a = bv[0]; for (int k = 0; k < 256; ++k) a += rl[k] * Wv[k]; }
    hd[t] = a;
  }
  __syncthreads();
  for (int s = 128; s > 0; s >>= 1) { if (t < s) red[t] += red[t + s]; __syncthreads(); }
  const float dirn = y / fmaxf(sqrtf(red[0]), 1e-12f);
  if (t == 0) {
    const float l0 = hd[0], l1 = hd[1];
    uint32_t a0, a1, c0, c1;
    threefry2x32(0u, 1u, 0u, (uint32_t)(2 * b), a0, a1);
    threefry2x32(0u, 1u, 0u, (uint32_t)(2 * b + 1), c0, c1);
    const float g0 = gumbel_from_bits(a0 ^ a1);
    const float g1 = gumbel_from_bits(c0 ^ c1);
    const int act = (l1 + g1 > l0 + g0) ? 1 : 0;
    const float mx = fmaxf(l0, l1);
    const float lse = mx + logf(expf(l0 - mx) + expf(l1 - mx));
    const float lp0 = l0 - lse, lp1 = l1 - lse;
    out[OFF_ACT + b] = (float)act;
    out[OFF_LP + b] = act ? lp1 : lp0;
    out[OFF_VAL + b] = hd[3];
    out[OFF_ENT + b] = -(expf(lp0) * lp0 + expf(lp1) * lp1);
    hd[4] = 2.0f / (1.0f + expf(-hd[2]));
  }
  __syncthreads();
  out[OFF_POS + b * 256 + t] = rl[t] + hd[4] * dirn;
}

// ---------------------------------------------------------------- launch
extern "C" void kernel_launch(void* const* d_in, const int* in_sizes, int n_in,
                              void* d_out, int out_size, void* d_ws, size_t ws_size,
                              hipStream_t stream) {
  const float* state = (const float*)d_in[0];
  const float* bank  = (const float*)d_in[1];
  const float* vals  = (const float*)d_in[2];
  const float* W1  = (const float*)d_in[3];
  const float* b1  = (const float*)d_in[4];
  const float* W2  = (const float*)d_in[5];
  const float* b2  = (const float*)d_in[6];
  const float* Wc  = (const float*)d_in[7];
  const float* bc  = (const float*)d_in[8];
  const float* Wd  = (const float*)d_in[9];
  const float* bd  = (const float*)d_in[10];
  const float* Wsw = (const float*)d_in[11];
  const float* bsw = (const float*)d_in[12];
  const float* Wv  = (const float*)d_in[13];
  const float* bv  = (const float*)d_in[14];
  const float* T1w = (const float*)d_in[15];
  const float* t1b = (const float*)d_in[16];
  const float* T2w = (const float*)d_in[17];
  const float* t2b = (const float*)d_in[18];
  float* out = (float*)d_out;
  float* ws = (float*)d_ws;

  // workspace layout (floats). regA (2,097,152) holds W1 partials (8x131072)
  // and later T2 partials (4x524288); cs/ci overlap its head (dead interval).
  float* regA = ws;                   // 2,097,152
  float* cs   = ws;                   // 250,368 (128*489*4)  [overlaps regA]
  int*   ci   = (int*)(ws + 250368);  // 250,368              [overlaps regA]
  float* h1   = ws + 2097152;         // 131072
  float* regC = ws + 2228224;         // 524,288 (W2 partials 8x32768 / T1 partials 4x131072)
  float* r0   = ws + 2752512;         // 32768
  float* rnm  = ws + 2785280;         // 32768
  float* h2   = ws + 2818048;         // 131072  -> base end 2,949,120

  // path-A extras
  uint32_t* rnbf   = (uint32_t*)(ws + 2949120);   // 16,384 u32
  uint32_t* bankbf = (uint32_t*)(ws + 2965504);   // NPAD*128 u32
  const size_t NEED_BYTES = (size_t)(2965504 + (size_t)NPAD * 128) * 4;  // ~268 MB
  const bool pathA = ws_size >= NEED_BYTES;

  // state_projection: H -> H/4 (relu) -> R
  gemm_tile<<<dim3(16, 2, 8), 256, 0, stream>>>(state, W1, regA, 128, 1024, 4096, 512);
  combine_z<8, true><<<512, 256, 0, stream>>>(regA, b1, h1, 131072, 1023);
  gemm_tile<<<dim3(4, 2, 8), 256, 0, stream>>>(h1, W2, regC, 128, 256, 1024, 128);
  combine_r0<<<128, 256, 0, stream>>>(regC, b2, r0, rnm, pathA ? rnbf : nullptr);
  // retrieval
  if (pathA) {
    prep_bank<<<2048, 256, 0, stream>>>(bank, vals, bankbf);
    sims_topk_a<<<NCHUNK, 512, 0, stream>>>(rnbf, bankbf, cs, ci);
  } else {
    sims_topk_b<<<NCHUNK, 256, 0, stream>>>(rnm, bank, vals, cs, ci);
  }
  topk_heads<<<128, 256, 0, stream>>>(cs, ci, bank, vals, rnm, r0,
                                      Wc, bc, Wd, bd, Wsw, bsw, Wv, bv, out);
  // thought_projection: R -> H/4 (relu) -> H  (K-split for parallelism)
  gemm_tile<<<dim3(16, 2, 4), 256, 0, stream>>>(out + OFF_POS, T1w, regC, 128, 1024, 256, 64);
  combine_z<4, true><<<512, 256, 0, stream>>>(regC, t1b, h2, 131072, 1023);
  gemm_tile<<<dim3(64, 2, 4), 256, 0, stream>>>(h2, T2w, regA, 128, 4096, 1024, 256);
  combine_z<4, false><<<2048, 256, 0, stream>>>(regA, t2b, out + OFF_LATENT, 524288, 4095);
}

// Round 17
// 417.190 us; speedup vs baseline: 1.2070x; 1.0789x over previous
//
#include <hip/hip_runtime.h>
#include <hip/hip_bf16.h>
#include <math.h>
#include <stdint.h>

// Problem constants (CoconutPPO): B=128, H=4096, R=256, M=500000, K=3
#define BB 128
#define HH 4096
#define RR 256
#define M_TOT 500000
#define CHUNK 2048
#define NCHUNK ((M_TOT + CHUNK - 1) / CHUNK)   // 245
#define NSUB (CHUNK / 32)                      // 64 subs of 32 rows
#define TINYF 1.17549435e-38f

// d_out layout (floats, concatenated in return order)
#define OFF_LATENT 0
#define OFF_POS    524288
#define OFF_ACT    557056
#define OFF_LP     557184
#define OFF_VAL    557312
#define OFF_ENT    557440

typedef __attribute__((ext_vector_type(8))) short bf16x8;
typedef __attribute__((ext_vector_type(4))) float f32x4;

// ---------------------------------------------------------------- helpers
__device__ __forceinline__ bool better(float a, int ia, float b, int ib) {
  return a > b || (a == b && ia < ib);
}
__device__ __forceinline__ void ins4_nd(float s, int id, float (&vs)[4], int (&vi)[4]) {
  if (better(s, id, vs[3], vi[3])) {
    vs[3] = s; vi[3] = id;
    if (better(vs[3], vi[3], vs[2], vi[2])) { float a=vs[3]; vs[3]=vs[2]; vs[2]=a; int x=vi[3]; vi[3]=vi[2]; vi[2]=x; }
    if (better(vs[2], vi[2], vs[1], vi[1])) { float a=vs[2]; vs[2]=vs[1]; vs[1]=a; int x=vi[2]; vi[2]=vi[1]; vi[1]=x; }
    if (better(vs[1], vi[1], vs[0], vi[0])) { float a=vs[1]; vs[1]=vs[0]; vs[0]=a; int x=vi[1]; vi[1]=vi[0]; vi[0]=x; }
  }
}
__device__ __forceinline__ void ins4(float s, int id, float (&vs)[4], int (&vi)[4]) {
  if (id == vi[0] || id == vi[1] || id == vi[2] || id == vi[3]) return;
  ins4_nd(s, id, vs, vi);
}
__device__ __forceinline__ void ins3(float s, int id, float (&vs)[3], int (&vi)[3]) {
  if (id == vi[0] || id == vi[1] || id == vi[2]) return;
  if (better(s, id, vs[2], vi[2])) {
    vs[2] = s; vi[2] = id;
    if (better(vs[2], vi[2], vs[1], vi[1])) { float a=vs[2]; vs[2]=vs[1]; vs[1]=a; int x=vi[2]; vi[2]=vi[1]; vi[1]=x; }
    if (better(vs[1], vi[1], vs[0], vi[0])) { float a=vs[1]; vs[1]=vs[0]; vs[0]=a; int x=vi[1]; vi[1]=vi[0]; vi[0]=x; }
  }
}
__device__ __forceinline__ void ins8(float s, int id, float (&vs)[8], int (&vi)[8]) {
#pragma unroll
  for (int q = 0; q < 8; ++q) if (id == vi[q]) return;
  if (!better(s, id, vs[7], vi[7])) return;
  vs[7] = s; vi[7] = id;
#pragma unroll
  for (int q = 7; q > 0; --q)
    if (better(vs[q], vi[q], vs[q-1], vi[q-1])) {
      float a = vs[q]; vs[q] = vs[q-1]; vs[q-1] = a;
      int x = vi[q]; vi[q] = vi[q-1]; vi[q-1] = x;
    }
}

// RNE f32 -> bf16 (bit arithmetic; matches hardware/NumPy RNE)
__device__ __forceinline__ uint32_t rne_u(float x) {
  uint32_t u = __float_as_uint(x);
  return (u + 0x7fffu + ((u >> 16) & 1u)) >> 16;
}
__device__ __forceinline__ uint32_t pk_bf16(float lo, float hi) {
  return rne_u(lo) | (rne_u(hi) << 16);
}

// async global->LDS (wave-uniform LDS base, per-lane global source)
__device__ __forceinline__ void load_lds16(const void* g, void* l) {
  __builtin_amdgcn_global_load_lds((const __attribute__((address_space(1))) void*)g,
                                   (__attribute__((address_space(3))) void*)l, 16, 0, 0);
}
__device__ __forceinline__ void load_lds4(const void* g, void* l) {
  __builtin_amdgcn_global_load_lds((const __attribute__((address_space(1))) void*)g,
                                   (__attribute__((address_space(3))) void*)l, 4, 0, 0);
}

#define TF_ROUND(r) { x0 += x1; x1 = (x1 << (r)) | (x1 >> (32 - (r))); x1 ^= x0; }
__device__ __forceinline__ void threefry2x32(uint32_t k0, uint32_t k1,
                                             uint32_t x0, uint32_t x1,
                                             uint32_t& o0, uint32_t& o1) {
  const uint32_t ks2 = k0 ^ k1 ^ 0x1BD11BDAu;
  x0 += k0; x1 += k1;
  TF_ROUND(13) TF_ROUND(15) TF_ROUND(26) TF_ROUND(6)
  x0 += k1; x1 += ks2 + 1u;
  TF_ROUND(17) TF_ROUND(29) TF_ROUND(16) TF_ROUND(24)
  x0 += ks2; x1 += k0 + 2u;
  TF_ROUND(13) TF_ROUND(15) TF_ROUND(26) TF_ROUND(6)
  x0 += k0; x1 += k1 + 3u;
  TF_ROUND(17) TF_ROUND(29) TF_ROUND(16) TF_ROUND(24)
  x0 += k1; x1 += ks2 + 4u;
  TF_ROUND(13) TF_ROUND(15) TF_ROUND(26) TF_ROUND(6)
  x0 += ks2; x1 += k0 + 5u;
  o0 = x0; o1 = x1;
}

__device__ __forceinline__ float gumbel_from_bits(uint32_t bits) {
  const uint32_t fb = (bits >> 9) | 0x3f800000u;
  const float fl = __uint_as_float(fb) - 1.0f;
  const float u = fmaxf(TINYF, fl * (1.0f - TINYF) + TINYF);
  return -logf(-logf(u));
}

// ---------------------------------------------------------------- generic fp32 GEMM (partial slabs)
__global__ __launch_bounds__(256)
void gemm_tile(const float* __restrict__ A, const float* __restrict__ Bw,
               float* __restrict__ C, int Mr, int Nc, int K, int klen) {
  __shared__ float As[16][68];
  __shared__ float Bs[16][68];
  const int col0 = blockIdx.x * 64;
  const int row0 = blockIdx.y * 64;
  const int k0 = blockIdx.z * klen;
  const int t = threadIdx.x;
  const int tc = t & 15, tr = t >> 4;
  float acc[4][4] = {};
  for (int kk = k0; kk < k0 + klen; kk += 16) {
    {
      const int r = t >> 2, c4 = (t & 3) << 2;
      const float4 v = *reinterpret_cast<const float4*>(A + (size_t)(row0 + r) * K + kk + c4);
      As[c4 + 0][r] = v.x; As[c4 + 1][r] = v.y; As[c4 + 2][r] = v.z; As[c4 + 3][r] = v.w;
    }
    {
      const int kr = t >> 4, c4 = (t & 15) << 2;
      const float4 v = *reinterpret_cast<const float4*>(Bw + (size_t)(kk + kr) * Nc + col0 + c4);
      *reinterpret_cast<float4*>(&Bs[kr][c4]) = v;
    }
    __syncthreads();
#pragma unroll
    for (int k = 0; k < 16; ++k) {
      const float4 a4 = *reinterpret_cast<const float4*>(&As[k][tr * 4]);
      const float4 b4 = *reinterpret_cast<const float4*>(&Bs[k][tc * 4]);
      float a[4] = {a4.x, a4.y, a4.z, a4.w};
      float b[4] = {b4.x, b4.y, b4.z, b4.w};
#pragma unroll
      for (int i = 0; i < 4; ++i)
#pragma unroll
        for (int j = 0; j < 4; ++j) acc[i][j] += a[i] * b[j];
    }
    __syncthreads();
  }
  float* Cp = C + (size_t)blockIdx.z * Mr * Nc;
#pragma unroll
  for (int i = 0; i < 4; ++i) {
    const int row = row0 + tr * 4 + i;
#pragma unroll
    for (int j = 0; j < 4; ++j) {
      Cp[(size_t)row * Nc + col0 + tc * 4 + j] = acc[i][j];
    }
  }
}

// ---------------------------------------------------------------- combines
template<int Z, bool RELU>
__global__ void combine_z(const float* __restrict__ src, const float* __restrict__ bias,
                          float* __restrict__ dst, int total, int mask) {
  const int i = blockIdx.x * 256 + threadIdx.x;
  float v = bias[i & mask];
#pragma unroll
  for (int z = 0; z < Z; ++z) v += src[(size_t)z * total + i];
  dst[i] = RELU ? fmaxf(v, 0.0f) : v;
}

__global__ __launch_bounds__(256)
void combine_r0(const float* __restrict__ r0p, const float* __restrict__ b2,
                float* __restrict__ r0, float* __restrict__ rnorm,
                uint32_t* __restrict__ rnbf) {
  const int b = blockIdx.x, t = threadIdx.x;
  __shared__ float red[256];
  __shared__ float vtmp[256];
  float v = b2[t];
#pragma unroll
  for (int z = 0; z < 8; ++z) v += r0p[z * 32768 + b * 256 + t];
  r0[b * 256 + t] = v;
  red[t] = v * v;
  __syncthreads();
  for (int s = 128; s > 0; s >>= 1) { if (t < s) red[t] += red[t + s]; __syncthreads(); }
  const float inv = 1.0f / fmaxf(sqrtf(red[0]), 1e-12f);
  const float vn = v * inv;
  rnorm[b * 256 + t] = vn;
  vtmp[t] = vn;
  __syncthreads();
  if (t < 128) rnbf[b * 128 + t] = pk_bf16(vtmp[2 * t], vtmp[2 * t + 1]);
}

// ---------------------------------------------------------------- FUSED MFMA sims (single pass over fp32 bank)
// 512 thr / 8 waves, 152 KB LDS -> 1 block/CU; 245 blocks = one scheduling
// wave. Per chunk (2048 rows): 64 subs of 32 rows. 3-deep counted-vmcnt
// async pipeline of RAW FP32 rows (gload_lds); each wave converts exactly
// the rows it loaded (wave-private fp32 bufs): sumsq -> wscale -> prescaled
// bf16 swizzled tile (mod-3 parity => one lgkmcnt+barrier per iteration is
// race-free). vals prefetched to LDS in the prologue. Saves the 512 MB
// prep-write + re-read of rounds 12-16.
__global__ __launch_bounds__(512)
void sims_fused(const uint32_t* __restrict__ rnbf, const float* __restrict__ bank,
                const float* __restrict__ vals, float* __restrict__ cand_s,
                int* __restrict__ cand_i) {
  __shared__ __align__(16) float fA[3][32 * 256];           // 3 x 32 KB raw fp32 rows
  __shared__ __align__(16) unsigned short tB[3][32 * 256];  // 3 x 16 KB prescaled bf16 (swz)
  __shared__ float valsL[CHUNK];                            // 8 KB

  const int t = threadIdx.x;
  const int lane = t & 63;
  const int w = t >> 6;            // wave 0..7 -> batch rows w*16..w*16+15
  const int fr = lane & 15;
  const int fq = lane >> 4;        // 0..3 (k-group)
  const int cbase = blockIdx.x * CHUNK;

  // ---- B-frags (one 16-row batch set per wave) from bf16 rnorm
  bf16x8 Bf[8];
  {
    const uint4* rp = reinterpret_cast<const uint4*>(rnbf + (size_t)(w * 16 + fr) * 128);
#pragma unroll
    for (int ks = 0; ks < 8; ++ks) {
      uint4 u = rp[ks * 4 + fq];
      Bf[ks] = *reinterpret_cast<bf16x8*>(&u);
    }
  }

  float ts[4]; int ti[4];
#pragma unroll
  for (int q = 0; q < 4; ++q) { ts[q] = -INFINITY; ti[q] = 0x7ffffff0 + q; }

  // issue raw fp32 rows of sub s (wave w loads rows w*4..w*4+4; 4 x 1KB)
  auto issue = [&](int s) {
    float* buf = fA[s % 3];
#pragma unroll
    for (int j = 0; j < 4; ++j) {
      const int r = w * 4 + j;
      int m = cbase + s * 32 + r;
      if (m > M_TOT - 1) m = M_TOT - 1;          // clamp: row skipped in epilogue
      load_lds16(bank + (size_t)m * 256 + lane * 4,
                 reinterpret_cast<char*>(buf) + r * 1024);
    }
  };

  // convert sub s: wave-private fp32 rows -> prescaled bf16 swizzled tile
  auto convert = [&](int s) {
    const float* src = fA[s % 3];
    unsigned short* dst = tB[s % 3];
#pragma unroll
    for (int j = 0; j < 4; ++j) {
      const int r = w * 4 + j;
      const float4 v = *reinterpret_cast<const float4*>(src + r * 256 + lane * 4);
      float ssq = v.x * v.x + v.y * v.y + v.z * v.z + v.w * v.w;
#pragma unroll
      for (int msk = 1; msk < 64; msk <<= 1) ssq += __shfl_xor(ssq, msk);
      const float vv = valsL[s * 32 + r];
      const float wsc = (vv + 1e-8f) / fmaxf(sqrtf(ssq), 1e-12f);
      uint2 p;
      p.x = pk_bf16(v.x * wsc, v.y * wsc);
      p.y = pk_bf16(v.z * wsc, v.w * wsc);
      const int c = lane >> 1, h = lane & 1;
      *reinterpret_cast<uint2*>(
          reinterpret_cast<char*>(dst) + r * 512 + (((c ^ (r & 7)) << 4) + h * 8)) = p;
    }
  };

  // ---- prologue: vals (4 loads/wave) then fp32 subs 0,1,2 (4 loads each)
#pragma unroll
  for (int j = 0; j < 4; ++j) {
    const int seg = w * 4 + j;                   // 0..31, 64 floats each
    int mi = cbase + seg * 64 + lane;
    if (mi > M_TOT - 1) mi = M_TOT - 1;
    load_lds4(vals + mi, reinterpret_cast<char*>(valsL) + seg * 256);
  }
  issue(0); issue(1); issue(2);
  asm volatile("s_waitcnt vmcnt(8)" ::: "memory");   // vals + sub0 landed (per wave)
  __builtin_amdgcn_sched_barrier(0);
  __builtin_amdgcn_s_barrier();                      // all waves: vals visible
  convert(0);
  asm volatile("s_waitcnt lgkmcnt(0)" ::: "memory");
  __builtin_amdgcn_sched_barrier(0);
  __builtin_amdgcn_s_barrier();                      // tB[0] visible
  issue(3);

  for (int s = 0; s < NSUB; ++s) {
    if (s < NSUB - 1) {
      // wait for sub s+1's fp32 (keep newer subs in flight; never drain mid-loop)
      if (s < NSUB - 3) {
        asm volatile("s_waitcnt vmcnt(8)" ::: "memory");
      } else if (s == NSUB - 3) {
        asm volatile("s_waitcnt vmcnt(4)" ::: "memory");
      } else {
        asm volatile("s_waitcnt vmcnt(0)" ::: "memory");
      }
      __builtin_amdgcn_sched_barrier(0);
      convert(s + 1);
      asm volatile("s_waitcnt lgkmcnt(0)" ::: "memory");
      __builtin_amdgcn_sched_barrier(0);
      __builtin_amdgcn_s_barrier();                  // tB[(s+1)%3] visible; fA[(s+1)%3] free
      if (s + 4 < NSUB) issue(s + 4);                // reuses fA[(s+1)%3]
    }

    // ---- MFMA: 32 mem rows x 16 batch rows (this wave's set) on tB[s%3]
    const unsigned short* tc = tB[s % 3];
    f32x4 acc[2];
#pragma unroll
    for (int mt = 0; mt < 2; ++mt) acc[mt] = (f32x4){0.f, 0.f, 0.f, 0.f};
#pragma unroll
    for (int ks = 0; ks < 8; ++ks) {
      const int kc = ks * 4 + fq;
#pragma unroll
      for (int mt = 0; mt < 2; ++mt) {
        const int rA = mt * 16 + fr;
        const bf16x8 a = *reinterpret_cast<const bf16x8*>(
            tc + rA * 256 + ((kc ^ (rA & 7)) << 3));
        acc[mt] = __builtin_amdgcn_mfma_f32_16x16x32_bf16(a, Bf[ks], acc[mt], 0, 0, 0);
      }
    }
    // ---- epilogue: prescaled scores -> per-lane top-4
    const int m_base = cbase + s * 32;
#pragma unroll
    for (int mt = 0; mt < 2; ++mt)
#pragma unroll
      for (int j = 0; j < 4; ++j) {
        const int ml = mt * 16 + fq * 4 + j;
        const int mm = m_base + ml;
        if (mm < M_TOT) ins4_nd(acc[mt][j], mm, ts, ti);
      }
  }

  // merge the 4 fq-lane groups sharing each batch row (snapshot butterfly)
#pragma unroll
  for (int mask = 16; mask < 64; mask <<= 1) {
    float os[4]; int oi[4];
#pragma unroll
    for (int q = 0; q < 4; ++q) {
      os[q] = __shfl_xor(ts[q], mask);
      oi[q] = __shfl_xor(ti[q], mask);
    }
#pragma unroll
    for (int q = 0; q < 4; ++q) ins4(os[q], oi[q], ts, ti);
  }
  if (fq == 0) {
    const int b = w * 16 + fr;
    const size_t base = ((size_t)b * NCHUNK + blockIdx.x) * 4;
#pragma unroll
    for (int q = 0; q < 4; ++q) { cand_s[base + q] = ts[q]; cand_i[base + q] = ti[q]; }
  }
}

// ---------------------------------------------------------------- merge + rescore + fuse + policy heads (fused)
__global__ __launch_bounds__(256)
void topk_heads(const float* __restrict__ cand_s, const int* __restrict__ cand_i,
                const float* __restrict__ bank, const float* __restrict__ vals,
                const float* __restrict__ rnorm, const float* __restrict__ r0,
                const float* __restrict__ Wc, const float* __restrict__ bc,
                const float* __restrict__ Wd, const float* __restrict__ bd,
                const float* __restrict__ Wsw, const float* __restrict__ bsw,
                const float* __restrict__ Wv, const float* __restrict__ bv,
                float* __restrict__ out) {
  const int b = blockIdx.x, t = threadIdx.x;
  __shared__ float rnL[256];
  __shared__ float ss[2048];
  __shared__ int   si[2048];
  __shared__ int   g8[8];
  __shared__ float sc8[8];
  __shared__ int   gidx[3];
  __shared__ float rl[256];
  __shared__ float red[256];
  __shared__ float hd[8];

  rnL[t] = rnorm[b * 256 + t];

  float ts[8]; int ti[8];
#pragma unroll
  for (int q = 0; q < 8; ++q) { ts[q] = -INFINITY; ti[q] = 0x7fffff00 + t * 8 + q; }
  const int n = NCHUNK * 4;
  const size_t base = (size_t)b * n;
  for (int c = t; c < n; c += 256) ins8(cand_s[base + c], cand_i[base + c], ts, ti);
#pragma unroll
  for (int q = 0; q < 8; ++q) { ss[t * 8 + q] = ts[q]; si[t * 8 + q] = ti[q]; }
  __syncthreads();

  if (t < 64) {
    float ms[8]; int mi[8];
#pragma unroll
    for (int q = 0; q < 8; ++q) { ms[q] = -INFINITY; mi[q] = 0x7ffffe00 + t * 8 + q; }
    for (int c = t * 32; c < t * 32 + 32; ++c) ins8(ss[c], si[c], ms, mi);
#pragma unroll
    for (int mask = 1; mask < 64; mask <<= 1) {
      float os[8]; int oi[8];
#pragma unroll
      for (int q = 0; q < 8; ++q) { os[q] = __shfl_xor(ms[q], mask); oi[q] = __shfl_xor(mi[q], mask); }
#pragma unroll
      for (int q = 0; q < 8; ++q) ins8(os[q], oi[q], ms, mi);
    }
    if (t == 0) {
#pragma unroll
      for (int q = 0; q < 8; ++q) g8[q] = mi[q];
    }
  }
  __syncthreads();

  {
    const int c = t >> 5, g = t & 31;
    const int id = g8[c];
    float ssq = 0.0f, dt = 0.0f;
    if (id < M_TOT) {
      const float4* bp = reinterpret_cast<const float4*>(bank + (size_t)id * 256);
      const float4 x0 = bp[g * 2], x1 = bp[g * 2 + 1];
      const float4 r0v = *reinterpret_cast<const float4*>(&rnL[g * 8]);
      const float4 r1v = *reinterpret_cast<const float4*>(&rnL[g * 8 + 4]);
      ssq = x0.x*x0.x + x0.y*x0.y + x0.z*x0.z + x0.w*x0.w +
            x1.x*x1.x + x1.y*x1.y + x1.z*x1.z + x1.w*x1.w;
      dt  = x0.x*r0v.x + x0.y*r0v.y + x0.z*r0v.z + x0.w*r0v.w +
            x1.x*r1v.x + x1.y*r1v.y + x1.z*r1v.z + x1.w*r1v.w;
    }
#pragma unroll
    for (int mask = 1; mask < 32; mask <<= 1) { ssq += __shfl_xor(ssq, mask); dt += __shfl_xor(dt, mask); }
    if (g == 0)
      sc8[c] = (id < M_TOT)
                 ? dt * (1.0f / fmaxf(sqrtf(ssq), 1e-12f)) * (vals[id] + 1e-8f)
                 : -INFINITY;
  }
  __syncthreads();

  if (t == 0) {
    float gs[3] = {-INFINITY, -INFINITY, -INFINITY};
    int gi[3] = {0x7fffffff, 0x7ffffffe, 0x7ffffffd};
#pragma unroll
    for (int q = 0; q < 8; ++q) ins3(sc8[q], g8[q], gs, gi);
    gidx[0] = gi[0]; gidx[1] = gi[1]; gidx[2] = gi[2];
  }
  __syncthreads();

  {
    const int i0 = gidx[0], i1 = gidx[1], i2 = gidx[2];
    const float retr = (bank[(size_t)i0 * 256 + t] + bank[(size_t)i1 * 256 + t] +
                        bank[(size_t)i2 * 256 + t]) / 3.0f;
    rl[t] = 0.5f * r0[b * 256 + t] + 0.5f * retr;
  }
  __syncthreads();

  float y = bd[t];
#pragma unroll 8
  for (int k = 0; k < 256; ++k) y += rl[k] * Wd[k * 256 + t];
  red[t] = y * y;
  if (t < 4) {
    float a;
    if (t == 0) { a = bc[0]; for (int k = 0; k < 256; ++k) a += rl[k] * Wc[2 * k]; }
    else if (t == 1) { a = bc[1]; for (int k = 0; k < 256; ++k) a += rl[k] * Wc[2 * k + 1]; }
    else if (t == 2) { a = bsw[0]; for (int k = 0; k < 256; ++k) a += rl[k] * Wsw[k]; }
    else { a = bv[0]; for (int k = 0; k < 256; ++k) a += rl[k] * Wv[k]; }
    hd[t] = a;
  }
  __syncthreads();
  for (int s = 128; s > 0; s >>= 1) { if (t < s) red[t] += red[t + s]; __syncthreads(); }
  const float dirn = y / fmaxf(sqrtf(red[0]), 1e-12f);
  if (t == 0) {
    const float l0 = hd[0], l1 = hd[1];
    uint32_t a0, a1, c0, c1;
    threefry2x32(0u, 1u, 0u, (uint32_t)(2 * b), a0, a1);
    threefry2x32(0u, 1u, 0u, (uint32_t)(2 * b + 1), c0, c1);
    const float g0 = gumbel_from_bits(a0 ^ a1);
    const float g1 = gumbel_from_bits(c0 ^ c1);
    const int act = (l1 + g1 > l0 + g0) ? 1 : 0;
    const float mx = fmaxf(l0, l1);
    const float lse = mx + logf(expf(l0 - mx) + expf(l1 - mx));
    const float lp0 = l0 - lse, lp1 = l1 - lse;
    out[OFF_ACT + b] = (float)act;
    out[OFF_LP + b] = act ? lp1 : lp0;
    out[OFF_VAL + b] = hd[3];
    out[OFF_ENT + b] = -(expf(lp0) * lp0 + expf(lp1) * lp1);
    hd[4] = 2.0f / (1.0f + expf(-hd[2]));
  }
  __syncthreads();
  out[OFF_POS + b * 256 + t] = rl[t] + hd[4] * dirn;
}

// ---------------------------------------------------------------- launch
extern "C" void kernel_launch(void* const* d_in, const int* in_sizes, int n_in,
                              void* d_out, int out_size, void* d_ws, size_t ws_size,
                              hipStream_t stream) {
  const float* state = (const float*)d_in[0];
  const float* bank  = (const float*)d_in[1];
  const float* vals  = (const float*)d_in[2];
  const float* W1  = (const float*)d_in[3];
  const float* b1  = (const float*)d_in[4];
  const float* W2  = (const float*)d_in[5];
  const float* b2  = (const float*)d_in[6];
  const float* Wc  = (const float*)d_in[7];
  const float* bc  = (const float*)d_in[8];
  const float* Wd  = (const float*)d_in[9];
  const float* bd  = (const float*)d_in[10];
  const float* Wsw = (const float*)d_in[11];
  const float* bsw = (const float*)d_in[12];
  const float* Wv  = (const float*)d_in[13];
  const float* bv  = (const float*)d_in[14];
  const float* T1w = (const float*)d_in[15];
  const float* t1b = (const float*)d_in[16];
  const float* T2w = (const float*)d_in[17];
  const float* t2b = (const float*)d_in[18];
  float* out = (float*)d_out;
  float* ws = (float*)d_ws;

  // workspace layout (floats). regA (2,097,152) holds W1 partials (8x131072)
  // and later T2 partials (4x524288); cs/ci overlap its head (dead interval:
  // written by sims_fused after combine_z consumed W1 partials, consumed by
  // topk_heads before the T2 gemm runs).
  float* regA = ws;                   // 2,097,152
  float* cs   = ws;                   // 125,440 (128*245*4)  [overlaps regA]
  int*   ci   = (int*)(ws + 125440);  // 125,440              [overlaps regA]
  float* h1   = ws + 2097152;         // 131072
  float* regC = ws + 2228224;         // 524,288 (W2 partials 8x32768 / T1 partials 4x131072)
  float* r0   = ws + 2752512;         // 32768
  float* rnm  = ws + 2785280;         // 32768
  float* h2   = ws + 2818048;         // 131072
  uint32_t* rnbf = (uint32_t*)(ws + 2949120);   // 16,384 u32 (bf16 rnorm)

  // state_projection: H -> H/4 (relu) -> R
  gemm_tile<<<dim3(16, 2, 8), 256, 0, stream>>>(state, W1, regA, 128, 1024, 4096, 512);
  combine_z<8, true><<<512, 256, 0, stream>>>(regA, b1, h1, 131072, 1023);
  gemm_tile<<<dim3(4, 2, 8), 256, 0, stream>>>(h1, W2, regC, 128, 256, 1024, 128);
  combine_r0<<<128, 256, 0, stream>>>(regC, b2, r0, rnm, rnbf);
  // retrieval: single-pass fused sims (no prep, no bank round-trip)
  sims_fused<<<NCHUNK, 512, 0, stream>>>(rnbf, bank, vals, cs, ci);
  topk_heads<<<128, 256, 0, stream>>>(cs, ci, bank, vals, rnm, r0,
                                      Wc, bc, Wd, bd, Wsw, bsw, Wv, bv, out);
  // thought_projection: R -> H/4 (relu) -> H  (K-split for parallelism)
  gemm_tile<<<dim3(16, 2, 4), 256, 0, stream>>>(out + OFF_POS, T1w, regC, 128, 1024, 256, 64);
  combine_z<4, true><<<512, 256, 0, stream>>>(regC, t1b, h2, 131072, 1023);
  gemm_tile<<<dim3(64, 2, 4), 256, 0, stream>>>(h2, T2w, regA, 128, 4096, 1024, 256);
  combine_z<4, false><<<2048, 256, 0, stream>>>(regA, t2b, out + OFF_LATENT, 524288, 4095);
}

// Round 18
// 392.043 us; speedup vs baseline: 1.2844x; 1.0641x over previous
//
#include <hip/hip_runtime.h>
#include <hip/hip_bf16.h>
#include <math.h>
#include <stdint.h>

// Problem constants (CoconutPPO): B=128, H=4096, R=256, M=500000, K=3
#define BB 128
#define HH 4096
#define RR 256
#define M_TOT 500000
#define CHUNK 1024
#define NCHUNK ((M_TOT + CHUNK - 1) / CHUNK)   // 489
#define NSUB (CHUNK / 16)                      // 64 subs of 16 rows
#define TINYF 1.17549435e-38f

// d_out layout (floats, concatenated in return order)
#define OFF_LATENT 0
#define OFF_POS    524288
#define OFF_ACT    557056
#define OFF_LP     557184
#define OFF_VAL    557312
#define OFF_ENT    557440

typedef __attribute__((ext_vector_type(8))) short bf16x8;
typedef __attribute__((ext_vector_type(4))) float f32x4;

// ---------------------------------------------------------------- helpers
__device__ __forceinline__ bool better(float a, int ia, float b, int ib) {
  return a > b || (a == b && ia < ib);
}
__device__ __forceinline__ void ins4_nd(float s, int id, float (&vs)[4], int (&vi)[4]) {
  if (better(s, id, vs[3], vi[3])) {
    vs[3] = s; vi[3] = id;
    if (better(vs[3], vi[3], vs[2], vi[2])) { float a=vs[3]; vs[3]=vs[2]; vs[2]=a; int x=vi[3]; vi[3]=vi[2]; vi[2]=x; }
    if (better(vs[2], vi[2], vs[1], vi[1])) { float a=vs[2]; vs[2]=vs[1]; vs[1]=a; int x=vi[2]; vi[2]=vi[1]; vi[1]=x; }
    if (better(vs[1], vi[1], vs[0], vi[0])) { float a=vs[1]; vs[1]=vs[0]; vs[0]=a; int x=vi[1]; vi[1]=vi[0]; vi[0]=x; }
  }
}
__device__ __forceinline__ void ins4(float s, int id, float (&vs)[4], int (&vi)[4]) {
  if (id == vi[0] || id == vi[1] || id == vi[2] || id == vi[3]) return;
  ins4_nd(s, id, vs, vi);
}
__device__ __forceinline__ void ins3(float s, int id, float (&vs)[3], int (&vi)[3]) {
  if (id == vi[0] || id == vi[1] || id == vi[2]) return;
  if (better(s, id, vs[2], vi[2])) {
    vs[2] = s; vi[2] = id;
    if (better(vs[2], vi[2], vs[1], vi[1])) { float a=vs[2]; vs[2]=vs[1]; vs[1]=a; int x=vi[2]; vi[2]=vi[1]; vi[1]=x; }
    if (better(vs[1], vi[1], vs[0], vi[0])) { float a=vs[1]; vs[1]=vs[0]; vs[0]=a; int x=vi[1]; vi[1]=vi[0]; vi[0]=x; }
  }
}
__device__ __forceinline__ void ins8(float s, int id, float (&vs)[8], int (&vi)[8]) {
#pragma unroll
  for (int q = 0; q < 8; ++q) if (id == vi[q]) return;
  if (!better(s, id, vs[7], vi[7])) return;
  vs[7] = s; vi[7] = id;
#pragma unroll
  for (int q = 7; q > 0; --q)
    if (better(vs[q], vi[q], vs[q-1], vi[q-1])) {
      float a = vs[q]; vs[q] = vs[q-1]; vs[q-1] = a;
      int x = vi[q]; vi[q] = vi[q-1]; vi[q-1] = x;
    }
}

// RNE f32 -> bf16 (bit arithmetic; matches hardware/NumPy RNE)
__device__ __forceinline__ uint32_t rne_u(float x) {
  uint32_t u = __float_as_uint(x);
  return (u + 0x7fffu + ((u >> 16) & 1u)) >> 16;
}
__device__ __forceinline__ uint32_t pk_bf16(float lo, float hi) {
  return rne_u(lo) | (rne_u(hi) << 16);
}

// async global->LDS (wave-uniform LDS base, per-lane global source)
__device__ __forceinline__ void load_lds16(const void* g, void* l) {
  __builtin_amdgcn_global_load_lds((const __attribute__((address_space(1))) void*)g,
                                   (__attribute__((address_space(3))) void*)l, 16, 0, 0);
}
__device__ __forceinline__ void load_lds4(const void* g, void* l) {
  __builtin_amdgcn_global_load_lds((const __attribute__((address_space(1))) void*)g,
                                   (__attribute__((address_space(3))) void*)l, 4, 0, 0);
}

#define TF_ROUND(r) { x0 += x1; x1 = (x1 << (r)) | (x1 >> (32 - (r))); x1 ^= x0; }
__device__ __forceinline__ void threefry2x32(uint32_t k0, uint32_t k1,
                                             uint32_t x0, uint32_t x1,
                                             uint32_t& o0, uint32_t& o1) {
  const uint32_t ks2 = k0 ^ k1 ^ 0x1BD11BDAu;
  x0 += k0; x1 += k1;
  TF_ROUND(13) TF_ROUND(15) TF_ROUND(26) TF_ROUND(6)
  x0 += k1; x1 += ks2 + 1u;
  TF_ROUND(17) TF_ROUND(29) TF_ROUND(16) TF_ROUND(24)
  x0 += ks2; x1 += k0 + 2u;
  TF_ROUND(13) TF_ROUND(15) TF_ROUND(26) TF_ROUND(6)
  x0 += k0; x1 += k1 + 3u;
  TF_ROUND(17) TF_ROUND(29) TF_ROUND(16) TF_ROUND(24)
  x0 += k1; x1 += ks2 + 4u;
  TF_ROUND(13) TF_ROUND(15) TF_ROUND(26) TF_ROUND(6)
  x0 += ks2; x1 += k0 + 5u;
  o0 = x0; o1 = x1;
}

__device__ __forceinline__ float gumbel_from_bits(uint32_t bits) {
  const uint32_t fb = (bits >> 9) | 0x3f800000u;
  const float fl = __uint_as_float(fb) - 1.0f;
  const float u = fmaxf(TINYF, fl * (1.0f - TINYF) + TINYF);
  return -logf(-logf(u));
}

// ---------------------------------------------------------------- generic fp32 GEMM (partial slabs)
__global__ __launch_bounds__(256)
void gemm_tile(const float* __restrict__ A, const float* __restrict__ Bw,
               float* __restrict__ C, int Mr, int Nc, int K, int klen) {
  __shared__ float As[16][68];
  __shared__ float Bs[16][68];
  const int col0 = blockIdx.x * 64;
  const int row0 = blockIdx.y * 64;
  const int k0 = blockIdx.z * klen;
  const int t = threadIdx.x;
  const int tc = t & 15, tr = t >> 4;
  float acc[4][4] = {};
  for (int kk = k0; kk < k0 + klen; kk += 16) {
    {
      const int r = t >> 2, c4 = (t & 3) << 2;
      const float4 v = *reinterpret_cast<const float4*>(A + (size_t)(row0 + r) * K + kk + c4);
      As[c4 + 0][r] = v.x; As[c4 + 1][r] = v.y; As[c4 + 2][r] = v.z; As[c4 + 3][r] = v.w;
    }
    {
      const int kr = t >> 4, c4 = (t & 15) << 2;
      const float4 v = *reinterpret_cast<const float4*>(Bw + (size_t)(kk + kr) * Nc + col0 + c4);
      *reinterpret_cast<float4*>(&Bs[kr][c4]) = v;
    }
    __syncthreads();
#pragma unroll
    for (int k = 0; k < 16; ++k) {
      const float4 a4 = *reinterpret_cast<const float4*>(&As[k][tr * 4]);
      const float4 b4 = *reinterpret_cast<const float4*>(&Bs[k][tc * 4]);
      float a[4] = {a4.x, a4.y, a4.z, a4.w};
      float b[4] = {b4.x, b4.y, b4.z, b4.w};
#pragma unroll
      for (int i = 0; i < 4; ++i)
#pragma unroll
        for (int j = 0; j < 4; ++j) acc[i][j] += a[i] * b[j];
    }
    __syncthreads();
  }
  float* Cp = C + (size_t)blockIdx.z * Mr * Nc;
#pragma unroll
  for (int i = 0; i < 4; ++i) {
    const int row = row0 + tr * 4 + i;
#pragma unroll
    for (int j = 0; j < 4; ++j) {
      Cp[(size_t)row * Nc + col0 + tc * 4 + j] = acc[i][j];
    }
  }
}

// ---------------------------------------------------------------- combines
template<int Z, bool RELU>
__global__ void combine_z(const float* __restrict__ src, const float* __restrict__ bias,
                          float* __restrict__ dst, int total, int mask) {
  const int i = blockIdx.x * 256 + threadIdx.x;
  float v = bias[i & mask];
#pragma unroll
  for (int z = 0; z < Z; ++z) v += src[(size_t)z * total + i];
  dst[i] = RELU ? fmaxf(v, 0.0f) : v;
}

__global__ __launch_bounds__(256)
void combine_r0(const float* __restrict__ r0p, const float* __restrict__ b2,
                float* __restrict__ r0, float* __restrict__ rnorm,
                uint32_t* __restrict__ rnbf) {
  const int b = blockIdx.x, t = threadIdx.x;
  __shared__ float red[256];
  __shared__ float vtmp[256];
  float v = b2[t];
#pragma unroll
  for (int z = 0; z < 8; ++z) v += r0p[z * 32768 + b * 256 + t];
  r0[b * 256 + t] = v;
  red[t] = v * v;
  __syncthreads();
  for (int s = 128; s > 0; s >>= 1) { if (t < s) red[t] += red[t + s]; __syncthreads(); }
  const float inv = 1.0f / fmaxf(sqrtf(red[0]), 1e-12f);
  const float vn = v * inv;
  rnorm[b * 256 + t] = vn;
  vtmp[t] = vn;
  __syncthreads();
  if (t < 128) rnbf[b * 128 + t] = pk_bf16(vtmp[2 * t], vtmp[2 * t + 1]);
}

// ---------------------------------------------------------------- FUSED MFMA sims (single pass over fp32 bank)
// 512 thr / 8 waves, 76 KB LDS -> 2 blocks/CU (two blocks anti-phase their
// load/convert/MFMA phases -> HBM stays fed through compute). 489 blocks =
// one balanced scheduling wave. 64 subs of 16 rows; 3-deep counted-vmcnt
// async pipeline of RAW fp32 rows (gload_lds); each wave converts the 2 rows
// it loaded (sumsq -> wscale -> prescaled bf16 swizzled tile; mod-3 parity
// => one lgkmcnt+barrier per iteration is race-free).
__global__ __launch_bounds__(512)
void sims_fused(const uint32_t* __restrict__ rnbf, const float* __restrict__ bank,
                const float* __restrict__ vals, float* __restrict__ cand_s,
                int* __restrict__ cand_i) {
  __shared__ __align__(16) float fA[3][16 * 256];           // 3 x 16 KB raw fp32 rows
  __shared__ __align__(16) unsigned short tB[3][16 * 256];  // 3 x 8 KB prescaled bf16 (swz)
  __shared__ float valsL[CHUNK];                            // 4 KB

  const int t = threadIdx.x;
  const int lane = t & 63;
  const int w = t >> 6;            // wave 0..7 -> batch rows w*16..w*16+15
  const int fr = lane & 15;
  const int fq = lane >> 4;        // 0..3 (k-group)
  const int cbase = blockIdx.x * CHUNK;

  // ---- B-frags (one 16-row batch set per wave) from bf16 rnorm
  bf16x8 Bf[8];
  {
    const uint4* rp = reinterpret_cast<const uint4*>(rnbf + (size_t)(w * 16 + fr) * 128);
#pragma unroll
    for (int ks = 0; ks < 8; ++ks) {
      uint4 u = rp[ks * 4 + fq];
      Bf[ks] = *reinterpret_cast<bf16x8*>(&u);
    }
  }

  float ts[4]; int ti[4];
#pragma unroll
  for (int q = 0; q < 4; ++q) { ts[q] = -INFINITY; ti[q] = 0x7ffffff0 + q; }

  // issue raw fp32 rows of sub s (wave w loads rows w*2, w*2+1; 2 x 1KB)
  auto issue = [&](int s) {
    float* buf = fA[s % 3];
#pragma unroll
    for (int j = 0; j < 2; ++j) {
      const int r = w * 2 + j;
      int m = cbase + s * 16 + r;
      if (m > M_TOT - 1) m = M_TOT - 1;          // clamp: row skipped in epilogue
      load_lds16(bank + (size_t)m * 256 + lane * 4,
                 reinterpret_cast<char*>(buf) + r * 1024);
    }
  };

  // convert sub s: wave-private fp32 rows -> prescaled bf16 swizzled tile
  auto convert = [&](int s) {
    const float* src = fA[s % 3];
    unsigned short* dst = tB[s % 3];
#pragma unroll
    for (int j = 0; j < 2; ++j) {
      const int r = w * 2 + j;
      const float4 v = *reinterpret_cast<const float4*>(src + r * 256 + lane * 4);
      float ssq = v.x * v.x + v.y * v.y + v.z * v.z + v.w * v.w;
#pragma unroll
      for (int msk = 1; msk < 64; msk <<= 1) ssq += __shfl_xor(ssq, msk);
      const float vv = valsL[s * 16 + r];
      const float wsc = (vv + 1e-8f) / fmaxf(sqrtf(ssq), 1e-12f);
      uint2 p;
      p.x = pk_bf16(v.x * wsc, v.y * wsc);
      p.y = pk_bf16(v.z * wsc, v.w * wsc);
      const int c = lane >> 1, h = lane & 1;
      *reinterpret_cast<uint2*>(
          reinterpret_cast<char*>(dst) + r * 512 + (((c ^ (r & 7)) << 4) + h * 8)) = p;
    }
  };

  // ---- prologue: vals (2 loads/wave; 16 segs of 64 floats) then subs 0,1,2
#pragma unroll
  for (int j = 0; j < 2; ++j) {
    const int seg = w * 2 + j;                   // 0..15
    int mi = cbase + seg * 64 + lane;
    if (mi > M_TOT - 1) mi = M_TOT - 1;
    load_lds4(vals + mi, reinterpret_cast<char*>(valsL) + seg * 256);
  }
  issue(0); issue(1); issue(2);
  asm volatile("s_waitcnt vmcnt(4)" ::: "memory");   // vals + sub0 landed (per wave)
  __builtin_amdgcn_sched_barrier(0);
  __builtin_amdgcn_s_barrier();                      // all waves: vals + fA[0] visible
  convert(0);
  asm volatile("s_waitcnt lgkmcnt(0)" ::: "memory");
  __builtin_amdgcn_sched_barrier(0);
  __builtin_amdgcn_s_barrier();                      // tB[0] visible
  issue(3);

  for (int s = 0; s < NSUB; ++s) {
    if (s < NSUB - 1) {
      // wait for sub s+1's fp32 (keep newer subs in flight; never drain mid-loop)
      if (s < NSUB - 3) {
        asm volatile("s_waitcnt vmcnt(4)" ::: "memory");
      } else if (s == NSUB - 3) {
        asm volatile("s_waitcnt vmcnt(2)" ::: "memory");
      } else {
        asm volatile("s_waitcnt vmcnt(0)" ::: "memory");
      }
      __builtin_amdgcn_sched_barrier(0);
      convert(s + 1);
      asm volatile("s_waitcnt lgkmcnt(0)" ::: "memory");
      __builtin_amdgcn_sched_barrier(0);
      __builtin_amdgcn_s_barrier();                  // tB[(s+1)%3] visible; fA[(s+1)%3] free
      if (s + 4 < NSUB) issue(s + 4);                // reuses fA[(s+1)%3]
    }

    // ---- MFMA: 16 mem rows x 16 batch rows (this wave's set) on tB[s%3]
    const unsigned short* tc = tB[s % 3];
    f32x4 acc = (f32x4){0.f, 0.f, 0.f, 0.f};
#pragma unroll
    for (int ks = 0; ks < 8; ++ks) {
      const int kc = ks * 4 + fq;
      const bf16x8 a = *reinterpret_cast<const bf16x8*>(
          tc + fr * 256 + ((kc ^ (fr & 7)) << 3));
      acc = __builtin_amdgcn_mfma_f32_16x16x32_bf16(a, Bf[ks], acc, 0, 0, 0);
    }
    // ---- epilogue: prescaled scores -> per-lane top-4
    const int m_base = cbase + s * 16;
#pragma unroll
    for (int j = 0; j < 4; ++j) {
      const int ml = fq * 4 + j;
      const int mm = m_base + ml;
      if (mm < M_TOT) ins4_nd(acc[j], mm, ts, ti);
    }
  }

  // merge the 4 fq-lane groups sharing each batch row (snapshot butterfly)
#pragma unroll
  for (int mask = 16; mask < 64; mask <<= 1) {
    float os[4]; int oi[4];
#pragma unroll
    for (int q = 0; q < 4; ++q) {
      os[q] = __shfl_xor(ts[q], mask);
      oi[q] = __shfl_xor(ti[q], mask);
    }
#pragma unroll
    for (int q = 0; q < 4; ++q) ins4(os[q], oi[q], ts, ti);
  }
  if (fq == 0) {
    const int b = w * 16 + fr;
    const size_t base = ((size_t)b * NCHUNK + blockIdx.x) * 4;
#pragma unroll
    for (int q = 0; q < 4; ++q) { cand_s[base + q] = ts[q]; cand_i[base + q] = ti[q]; }
  }
}

// ---------------------------------------------------------------- merge + rescore + fuse + policy heads (fused)
__global__ __launch_bounds__(256)
void topk_heads(const float* __restrict__ cand_s, const int* __restrict__ cand_i,
                const float* __restrict__ bank, const float* __restrict__ vals,
                const float* __restrict__ rnorm, const float* __restrict__ r0,
                const float* __restrict__ Wc, const float* __restrict__ bc,
                const float* __restrict__ Wd, const float* __restrict__ bd,
                const float* __restrict__ Wsw, const float* __restrict__ bsw,
                const float* __restrict__ Wv, const float* __restrict__ bv,
                float* __restrict__ out) {
  const int b = blockIdx.x, t = threadIdx.x;
  __shared__ float rnL[256];
  __shared__ float ss[2048];
  __shared__ int   si[2048];
  __shared__ int   g8[8];
  __shared__ float sc8[8];
  __shared__ int   gidx[3];
  __shared__ float rl[256];
  __shared__ float red[256];
  __shared__ float hd[8];

  rnL[t] = rnorm[b * 256 + t];

  float ts[8]; int ti[8];
#pragma unroll
  for (int q = 0; q < 8; ++q) { ts[q] = -INFINITY; ti[q] = 0x7fffff00 + t * 8 + q; }
  const int n = NCHUNK * 4;
  const size_t base = (size_t)b * n;
  for (int c = t; c < n; c += 256) ins8(cand_s[base + c], cand_i[base + c], ts, ti);
#pragma unroll
  for (int q = 0; q < 8; ++q) { ss[t * 8 + q] = ts[q]; si[t * 8 + q] = ti[q]; }
  __syncthreads();

  if (t < 64) {
    float ms[8]; int mi[8];
#pragma unroll
    for (int q = 0; q < 8; ++q) { ms[q] = -INFINITY; mi[q] = 0x7ffffe00 + t * 8 + q; }
    for (int c = t * 32; c < t * 32 + 32; ++c) ins8(ss[c], si[c], ms, mi);
#pragma unroll
    for (int mask = 1; mask < 64; mask <<= 1) {
      float os[8]; int oi[8];
#pragma unroll
      for (int q = 0; q < 8; ++q) { os[q] = __shfl_xor(ms[q], mask); oi[q] = __shfl_xor(mi[q], mask); }
#pragma unroll
      for (int q = 0; q < 8; ++q) ins8(os[q], oi[q], ms, mi);
    }
    if (t == 0) {
#pragma unroll
      for (int q = 0; q < 8; ++q) g8[q] = mi[q];
    }
  }
  __syncthreads();

  {
    const int c = t >> 5, g = t & 31;
    const int id = g8[c];
    float ssq = 0.0f, dt = 0.0f;
    if (id < M_TOT) {
      const float4* bp = reinterpret_cast<const float4*>(bank + (size_t)id * 256);
      const float4 x0 = bp[g * 2], x1 = bp[g * 2 + 1];
      const float4 r0v = *reinterpret_cast<const float4*>(&rnL[g * 8]);
      const float4 r1v = *reinterpret_cast<const float4*>(&rnL[g * 8 + 4]);
      ssq = x0.x*x0.x + x0.y*x0.y + x0.z*x0.z + x0.w*x0.w +
            x1.x*x1.x + x1.y*x1.y + x1.z*x1.z + x1.w*x1.w;
      dt  = x0.x*r0v.x + x0.y*r0v.y + x0.z*r0v.z + x0.w*r0v.w +
            x1.x*r1v.x + x1.y*r1v.y + x1.z*r1v.z + x1.w*r1v.w;
    }
#pragma unroll
    for (int mask = 1; mask < 32; mask <<= 1) { ssq += __shfl_xor(ssq, mask); dt += __shfl_xor(dt, mask); }
    if (g == 0)
      sc8[c] = (id < M_TOT)
                 ? dt * (1.0f / fmaxf(sqrtf(ssq), 1e-12f)) * (vals[id] + 1e-8f)
                 : -INFINITY;
  }
  __syncthreads();

  if (t == 0) {
    float gs[3] = {-INFINITY, -INFINITY, -INFINITY};
    int gi[3] = {0x7fffffff, 0x7ffffffe, 0x7ffffffd};
#pragma unroll
    for (int q = 0; q < 8; ++q) ins3(sc8[q], g8[q], gs, gi);
    gidx[0] = gi[0]; gidx[1] = gi[1]; gidx[2] = gi[2];
  }
  __syncthreads();

  {
    const int i0 = gidx[0], i1 = gidx[1], i2 = gidx[2];
    const float retr = (bank[(size_t)i0 * 256 + t] + bank[(size_t)i1 * 256 + t] +
                        bank[(size_t)i2 * 256 + t]) / 3.0f;
    rl[t] = 0.5f * r0[b * 256 + t] + 0.5f * retr;
  }
  __syncthreads();

  float y = bd[t];
#pragma unroll 8
  for (int k = 0; k < 256; ++k) y += rl[k] * Wd[k * 256 + t];
  red[t] = y * y;
  if (t < 4) {
    float a;
    if (t == 0) { a = bc[0]; for (int k = 0; k < 256; ++k) a += rl[k] * Wc[2 * k]; }
    else if (t == 1) { a = bc[1]; for (int k = 0; k < 256; ++k) a += rl[k] * Wc[2 * k + 1]; }
    else if (t == 2) { a = bsw[0]; for (int k = 0; k < 256; ++k) a += rl[k] * Wsw[k]; }
    else { a = bv[0]; for (int k = 0; k < 256; ++k) a += rl[k] * Wv[k]; }
    hd[t] = a;
  }
  __syncthreads();
  for (int s = 128; s > 0; s >>= 1) { if (t < s) red[t] += red[t + s]; __syncthreads(); }
  const float dirn = y / fmaxf(sqrtf(red[0]), 1e-12f);
  if (t == 0) {
    const float l0 = hd[0], l1 = hd[1];
    uint32_t a0, a1, c0, c1;
    threefry2x32(0u, 1u, 0u, (uint32_t)(2 * b), a0, a1);
    threefry2x32(0u, 1u, 0u, (uint32_t)(2 * b + 1), c0, c1);
    const float g0 = gumbel_from_bits(a0 ^ a1);
    const float g1 = gumbel_from_bits(c0 ^ c1);
    const int act = (l1 + g1 > l0 + g0) ? 1 : 0;
    const float mx = fmaxf(l0, l1);
    const float lse = mx + logf(expf(l0 - mx) + expf(l1 - mx));
    const float lp0 = l0 - lse, lp1 = l1 - lse;
    out[OFF_ACT + b] = (float)act;
    out[OFF_LP + b] = act ? lp1 : lp0;
    out[OFF_VAL + b] = hd[3];
    out[OFF_ENT + b] = -(expf(lp0) * lp0 + expf(lp1) * lp1);
    hd[4] = 2.0f / (1.0f + expf(-hd[2]));
  }
  __syncthreads();
  out[OFF_POS + b * 256 + t] = rl[t] + hd[4] * dirn;
}

// ---------------------------------------------------------------- launch
extern "C" void kernel_launch(void* const* d_in, const int* in_sizes, int n_in,
                              void* d_out, int out_size, void* d_ws, size_t ws_size,
                              hipStream_t stream) {
  const float* state = (const float*)d_in[0];
  const float* bank  = (const float*)d_in[1];
  const float* vals  = (const float*)d_in[2];
  const float* W1  = (const float*)d_in[3];
  const float* b1  = (const float*)d_in[4];
  const float* W2  = (const float*)d_in[5];
  const float* b2  = (const float*)d_in[6];
  const float* Wc  = (const float*)d_in[7];
  const float* bc  = (const float*)d_in[8];
  const float* Wd  = (const float*)d_in[9];
  const float* bd  = (const float*)d_in[10];
  const float* Wsw = (const float*)d_in[11];
  const float* bsw = (const float*)d_in[12];
  const float* Wv  = (const float*)d_in[13];
  const float* bv  = (const float*)d_in[14];
  const float* T1w = (const float*)d_in[15];
  const float* t1b = (const float*)d_in[16];
  const float* T2w = (const float*)d_in[17];
  const float* t2b = (const float*)d_in[18];
  float* out = (float*)d_out;
  float* ws = (float*)d_ws;

  // workspace layout (floats). regA (2,097,152) holds W1 partials (8x131072)
  // and later T2 partials (4x524288); cs/ci overlap its head (dead interval).
  float* regA = ws;                   // 2,097,152
  float* cs   = ws;                   // 250,368 (128*489*4)  [overlaps regA]
  int*   ci   = (int*)(ws + 250368);  // 250,368              [overlaps regA]
  float* h1   = ws + 2097152;         // 131072
  float* regC = ws + 2228224;         // 524,288 (W2 partials 8x32768 / T1 partials 4x131072)
  float* r0   = ws + 2752512;         // 32768
  float* rnm  = ws + 2785280;         // 32768
  float* h2   = ws + 2818048;         // 131072
  uint32_t* rnbf = (uint32_t*)(ws + 2949120);   // 16,384 u32 (bf16 rnorm)

  // state_projection: H -> H/4 (relu) -> R
  gemm_tile<<<dim3(16, 2, 8), 256, 0, stream>>>(state, W1, regA, 128, 1024, 4096, 512);
  combine_z<8, true><<<512, 256, 0, stream>>>(regA, b1, h1, 131072, 1023);
  gemm_tile<<<dim3(4, 2, 8), 256, 0, stream>>>(h1, W2, regC, 128, 256, 1024, 128);
  combine_r0<<<128, 256, 0, stream>>>(regC, b2, r0, rnm, rnbf);
  // retrieval: single-pass fused sims (no prep, no bank round-trip)
  sims_fused<<<NCHUNK, 512, 0, stream>>>(rnbf, bank, vals, cs, ci);
  topk_heads<<<128, 256, 0, stream>>>(cs, ci, bank, vals, rnm, r0,
                                      Wc, bc, Wd, bd, Wsw, bsw, Wv, bv, out);
  // thought_projection: R -> H/4 (relu) -> H  (K-split for parallelism)
  gemm_tile<<<dim3(16, 2, 4), 256, 0, stream>>>(out + OFF_POS, T1w, regC, 128, 1024, 256, 64);
  combine_z<4, true><<<512, 256, 0, stream>>>(regC, t1b, h2, 131072, 1023);
  gemm_tile<<<dim3(64, 2, 4), 256, 0, stream>>>(h2, T2w, regA, 128, 4096, 1024, 256);
  combine_z<4, false><<<2048, 256, 0, stream>>>(regA, t2b, out + OFF_LATENT, 524288, 4095);
}

// Round 19
// 317.738 us; speedup vs baseline: 1.5848x; 1.2339x over previous
//
#include <hip/hip_runtime.h>
#include <hip/hip_bf16.h>
#include <math.h>
#include <stdint.h>

// Problem constants (CoconutPPO): B=128, H=4096, R=256, M=500000, K=3
#define BB 128
#define HH 4096
#define RR 256
#define M_TOT 500000
#define CHUNK 1024
#define NCHUNK ((M_TOT + CHUNK - 1) / CHUNK)   // 489
#define NSUB (CHUNK / 16)                      // 64 subs of 16 rows
#define TINYF 1.17549435e-38f

// d_out layout (floats, concatenated in return order)
#define OFF_LATENT 0
#define OFF_POS    524288
#define OFF_ACT    557056
#define OFF_LP     557184
#define OFF_VAL    557312
#define OFF_ENT    557440

typedef __attribute__((ext_vector_type(8))) short bf16x8;
typedef __attribute__((ext_vector_type(4))) float f32x4;

// ---------------------------------------------------------------- helpers
__device__ __forceinline__ bool better(float a, int ia, float b, int ib) {
  return a > b || (a == b && ia < ib);
}
__device__ __forceinline__ void ins4_nd(float s, int id, float (&vs)[4], int (&vi)[4]) {
  if (better(s, id, vs[3], vi[3])) {
    vs[3] = s; vi[3] = id;
    if (better(vs[3], vi[3], vs[2], vi[2])) { float a=vs[3]; vs[3]=vs[2]; vs[2]=a; int x=vi[3]; vi[3]=vi[2]; vi[2]=x; }
    if (better(vs[2], vi[2], vs[1], vi[1])) { float a=vs[2]; vs[2]=vs[1]; vs[1]=a; int x=vi[2]; vi[2]=vi[1]; vi[1]=x; }
    if (better(vs[1], vi[1], vs[0], vi[0])) { float a=vs[1]; vs[1]=vs[0]; vs[0]=a; int x=vi[1]; vi[1]=vi[0]; vi[0]=x; }
  }
}
__device__ __forceinline__ void ins4(float s, int id, float (&vs)[4], int (&vi)[4]) {
  if (id == vi[0] || id == vi[1] || id == vi[2] || id == vi[3]) return;
  ins4_nd(s, id, vs, vi);
}
__device__ __forceinline__ void ins3(float s, int id, float (&vs)[3], int (&vi)[3]) {
  if (id == vi[0] || id == vi[1] || id == vi[2]) return;
  if (better(s, id, vs[2], vi[2])) {
    vs[2] = s; vi[2] = id;
    if (better(vs[2], vi[2], vs[1], vi[1])) { float a=vs[2]; vs[2]=vs[1]; vs[1]=a; int x=vi[2]; vi[2]=vi[1]; vi[1]=x; }
    if (better(vs[1], vi[1], vs[0], vi[0])) { float a=vs[1]; vs[1]=vs[0]; vs[0]=a; int x=vi[1]; vi[1]=vi[0]; vi[0]=x; }
  }
}
__device__ __forceinline__ void ins8(float s, int id, float (&vs)[8], int (&vi)[8]) {
#pragma unroll
  for (int q = 0; q < 8; ++q) if (id == vi[q]) return;
  if (!better(s, id, vs[7], vi[7])) return;
  vs[7] = s; vi[7] = id;
#pragma unroll
  for (int q = 7; q > 0; --q)
    if (better(vs[q], vi[q], vs[q-1], vi[q-1])) {
      float a = vs[q]; vs[q] = vs[q-1]; vs[q-1] = a;
      int x = vi[q]; vi[q] = vi[q-1]; vi[q-1] = x;
    }
}

// RNE f32 -> bf16 (bit arithmetic; matches hardware/NumPy RNE)
__device__ __forceinline__ uint32_t rne_u(float x) {
  uint32_t u = __float_as_uint(x);
  return (u + 0x7fffu + ((u >> 16) & 1u)) >> 16;
}
__device__ __forceinline__ uint32_t pk_bf16(float lo, float hi) {
  return rne_u(lo) | (rne_u(hi) << 16);
}

// async global->LDS (wave-uniform LDS base, per-lane global source)
__device__ __forceinline__ void load_lds4(const void* g, void* l) {
  __builtin_amdgcn_global_load_lds((const __attribute__((address_space(1))) void*)g,
                                   (__attribute__((address_space(3))) void*)l, 4, 0, 0);
}

#define TF_ROUND(r) { x0 += x1; x1 = (x1 << (r)) | (x1 >> (32 - (r))); x1 ^= x0; }
__device__ __forceinline__ void threefry2x32(uint32_t k0, uint32_t k1,
                                             uint32_t x0, uint32_t x1,
                                             uint32_t& o0, uint32_t& o1) {
  const uint32_t ks2 = k0 ^ k1 ^ 0x1BD11BDAu;
  x0 += k0; x1 += k1;
  TF_ROUND(13) TF_ROUND(15) TF_ROUND(26) TF_ROUND(6)
  x0 += k1; x1 += ks2 + 1u;
  TF_ROUND(17) TF_ROUND(29) TF_ROUND(16) TF_ROUND(24)
  x0 += ks2; x1 += k0 + 2u;
  TF_ROUND(13) TF_ROUND(15) TF_ROUND(26) TF_ROUND(6)
  x0 += k0; x1 += k1 + 3u;
  TF_ROUND(17) TF_ROUND(29) TF_ROUND(16) TF_ROUND(24)
  x0 += k1; x1 += ks2 + 4u;
  TF_ROUND(13) TF_ROUND(15) TF_ROUND(26) TF_ROUND(6)
  x0 += ks2; x1 += k0 + 5u;
  o0 = x0; o1 = x1;
}

__device__ __forceinline__ float gumbel_from_bits(uint32_t bits) {
  const uint32_t fb = (bits >> 9) | 0x3f800000u;
  const float fl = __uint_as_float(fb) - 1.0f;
  const float u = fmaxf(TINYF, fl * (1.0f - TINYF) + TINYF);
  return -logf(-logf(u));
}

// ---------------------------------------------------------------- generic fp32 GEMM (partial slabs)
__global__ __launch_bounds__(256)
void gemm_tile(const float* __restrict__ A, const float* __restrict__ Bw,
               float* __restrict__ C, int Mr, int Nc, int K, int klen) {
  __shared__ float As[16][68];
  __shared__ float Bs[16][68];
  const int col0 = blockIdx.x * 64;
  const int row0 = blockIdx.y * 64;
  const int k0 = blockIdx.z * klen;
  const int t = threadIdx.x;
  const int tc = t & 15, tr = t >> 4;
  float acc[4][4] = {};
  for (int kk = k0; kk < k0 + klen; kk += 16) {
    {
      const int r = t >> 2, c4 = (t & 3) << 2;
      const float4 v = *reinterpret_cast<const float4*>(A + (size_t)(row0 + r) * K + kk + c4);
      As[c4 + 0][r] = v.x; As[c4 + 1][r] = v.y; As[c4 + 2][r] = v.z; As[c4 + 3][r] = v.w;
    }
    {
      const int kr = t >> 4, c4 = (t & 15) << 2;
      const float4 v = *reinterpret_cast<const float4*>(Bw + (size_t)(kk + kr) * Nc + col0 + c4);
      *reinterpret_cast<float4*>(&Bs[kr][c4]) = v;
    }
    __syncthreads();
#pragma unroll
    for (int k = 0; k < 16; ++k) {
      const float4 a4 = *reinterpret_cast<const float4*>(&As[k][tr * 4]);
      const float4 b4 = *reinterpret_cast<const float4*>(&Bs[k][tc * 4]);
      float a[4] = {a4.x, a4.y, a4.z, a4.w};
      float b[4] = {b4.x, b4.y, b4.z, b4.w};
#pragma unroll
      for (int i = 0; i < 4; ++i)
#pragma unroll
        for (int j = 0; j < 4; ++j) acc[i][j] += a[i] * b[j];
    }
    __syncthreads();
  }
  float* Cp = C + (size_t)blockIdx.z * Mr * Nc;
#pragma unroll
  for (int i = 0; i < 4; ++i) {
    const int row = row0 + tr * 4 + i;
#pragma unroll
    for (int j = 0; j < 4; ++j) {
      Cp[(size_t)row * Nc + col0 + tc * 4 + j] = acc[i][j];
    }
  }
}

// ---------------------------------------------------------------- combines
template<int Z, bool RELU>
__global__ void combine_z(const float* __restrict__ src, const float* __restrict__ bias,
                          float* __restrict__ dst, int total, int mask) {
  const int i = blockIdx.x * 256 + threadIdx.x;
  float v = bias[i & mask];
#pragma unroll
  for (int z = 0; z < Z; ++z) v += src[(size_t)z * total + i];
  dst[i] = RELU ? fmaxf(v, 0.0f) : v;
}

__global__ __launch_bounds__(256)
void combine_r0(const float* __restrict__ r0p, const float* __restrict__ b2,
                float* __restrict__ r0, float* __restrict__ rnorm,
                uint32_t* __restrict__ rnbf) {
  const int b = blockIdx.x, t = threadIdx.x;
  __shared__ float red[256];
  __shared__ float vtmp[256];
  float v = b2[t];
#pragma unroll
  for (int z = 0; z < 8; ++z) v += r0p[z * 32768 + b * 256 + t];
  r0[b * 256 + t] = v;
  red[t] = v * v;
  __syncthreads();
  for (int s = 128; s > 0; s >>= 1) { if (t < s) red[t] += red[t + s]; __syncthreads(); }
  const float inv = 1.0f / fmaxf(sqrtf(red[0]), 1e-12f);
  const float vn = v * inv;
  rnorm[b * 256 + t] = vn;
  vtmp[t] = vn;
  __syncthreads();
  if (t < 128) rnbf[b * 128 + t] = pk_bf16(vtmp[2 * t], vtmp[2 * t + 1]);
}

// ---------------------------------------------------------------- FUSED MFMA sims (register-staged, max occupancy)
// 512 thr / 8 waves, 20 KB LDS + ~110 VGPR -> 4 blocks/CU, 32 waves/CU.
// 64 subs of 16 rows. fp32 rows staged in REGISTERS (2 named buffers pfA/pfB,
// loop unrolled x2 -- no dynamic indexing): each wave loads its 2 rows of
// sub s+2 right after converting sub s, so ~2 subs of HBM latency hide under
// compute; compiler inserts the vmcnt waits at consumption. tB (prescaled
// bf16, swizzled) is double-buffered; one raw s_barrier + lgkmcnt(0) per sub
// (vmcnt never drained mid-loop). Convert = sumsq shuffle-tree -> wscale ->
// pk_bf16, identical numerics to rounds 12-18.
__global__ __launch_bounds__(512, 4)
void sims_fused(const uint32_t* __restrict__ rnbf, const float* __restrict__ bank,
                const float* __restrict__ vals, float* __restrict__ cand_s,
                int* __restrict__ cand_i) {
  __shared__ __align__(16) unsigned short tB[2][16 * 256];  // 2 x 8 KB
  __shared__ float valsL[CHUNK];                            // 4 KB

  const int t = threadIdx.x;
  const int lane = t & 63;
  const int w = t >> 6;            // wave 0..7 -> batch rows w*16..w*16+15
  const int fr = lane & 15;
  const int fq = lane >> 4;        // 0..3 (k-group)
  const int cbase = blockIdx.x * CHUNK;

  // ---- B-frags (one 16-row batch set per wave) from bf16 rnorm
  bf16x8 Bf[8];
  {
    const uint4* rp = reinterpret_cast<const uint4*>(rnbf + (size_t)(w * 16 + fr) * 128);
#pragma unroll
    for (int ks = 0; ks < 8; ++ks) {
      uint4 u = rp[ks * 4 + fq];
      Bf[ks] = *reinterpret_cast<bf16x8*>(&u);
    }
  }

  float ts[4]; int ti[4];
#pragma unroll
  for (int q = 0; q < 4; ++q) { ts[q] = -INFINITY; ti[q] = 0x7ffffff0 + q; }

  float4 pA0, pA1, pB0, pB1;       // register staging (2 subs in flight)

  auto loadrow = [&](int m) -> float4 {
    if (m > M_TOT - 1) m = M_TOT - 1;          // clamp: row skipped in epilogue
    return *reinterpret_cast<const float4*>(bank + (size_t)m * 256 + lane * 4);
  };
  auto issueA = [&](int s) {
    pA0 = loadrow(cbase + s * 16 + w * 2);
    pA1 = loadrow(cbase + s * 16 + w * 2 + 1);
  };
  auto issueB = [&](int s) {
    pB0 = loadrow(cbase + s * 16 + w * 2);
    pB1 = loadrow(cbase + s * 16 + w * 2 + 1);
  };
  auto convrow = [&](const float4 v, int s, int r, unsigned short* dst) {
    float ssq = v.x * v.x + v.y * v.y + v.z * v.z + v.w * v.w;
#pragma unroll
    for (int msk = 1; msk < 64; msk <<= 1) ssq += __shfl_xor(ssq, msk);
    const float vv = valsL[s * 16 + r];
    const float wsc = (vv + 1e-8f) / fmaxf(sqrtf(ssq), 1e-12f);
    uint2 p;
    p.x = pk_bf16(v.x * wsc, v.y * wsc);
    p.y = pk_bf16(v.z * wsc, v.w * wsc);
    const int c = lane >> 1, h = lane & 1;
    *reinterpret_cast<uint2*>(
        reinterpret_cast<char*>(dst) + r * 512 + (((c ^ (r & 7)) << 4) + h * 8)) = p;
  };
  auto mfma_epi = [&](int s, const unsigned short* tc) {
    f32x4 acc = (f32x4){0.f, 0.f, 0.f, 0.f};
#pragma unroll
    for (int ks = 0; ks < 8; ++ks) {
      const int kc = ks * 4 + fq;
      const bf16x8 a = *reinterpret_cast<const bf16x8*>(
          tc + fr * 256 + ((kc ^ (fr & 7)) << 3));
      acc = __builtin_amdgcn_mfma_f32_16x16x32_bf16(a, Bf[ks], acc, 0, 0, 0);
    }
    const int m_base = cbase + s * 16;
#pragma unroll
    for (int j = 0; j < 4; ++j) {
      const int mm = m_base + fq * 4 + j;
      if (mm < M_TOT) ins4_nd(acc[j], mm, ts, ti);
    }
  };

  // ---- prologue: vals -> LDS (2 gload_lds4/wave), subs 0,1 -> registers
#pragma unroll
  for (int j = 0; j < 2; ++j) {
    const int seg = w * 2 + j;                   // 0..15, 64 floats each
    int mi = cbase + seg * 64 + lane;
    if (mi > M_TOT - 1) mi = M_TOT - 1;
    load_lds4(vals + mi, reinterpret_cast<char*>(valsL) + seg * 256);
  }
  issueA(0); issueB(1);
  asm volatile("s_waitcnt vmcnt(0)" ::: "memory");   // one-time full drain: valsL + pA/pB
  __builtin_amdgcn_sched_barrier(0);
  __builtin_amdgcn_s_barrier();                      // valsL visible

  for (int s2 = 0; s2 < NSUB; s2 += 2) {
    // ---- even sub (buffer A, tB[0])
    convrow(pA0, s2, w * 2, tB[0]);
    convrow(pA1, s2, w * 2 + 1, tB[0]);
    if (s2 + 2 < NSUB) issueA(s2 + 2);               // refill A: hides under barrier+MFMA
    asm volatile("s_waitcnt lgkmcnt(0)" ::: "memory");
    __builtin_amdgcn_sched_barrier(0);
    __builtin_amdgcn_s_barrier();                    // tB[0] visible to all
    mfma_epi(s2, tB[0]);
    // ---- odd sub (buffer B, tB[1])
    convrow(pB0, s2 + 1, w * 2, tB[1]);
    convrow(pB1, s2 + 1, w * 2 + 1, tB[1]);
    if (s2 + 3 < NSUB) issueB(s2 + 3);
    asm volatile("s_waitcnt lgkmcnt(0)" ::: "memory");
    __builtin_amdgcn_sched_barrier(0);
    __builtin_amdgcn_s_barrier();                    // tB[1] visible to all
    mfma_epi(s2 + 1, tB[1]);
  }

  // merge the 4 fq-lane groups sharing each batch row (snapshot butterfly)
#pragma unroll
  for (int mask = 16; mask < 64; mask <<= 1) {
    float os[4]; int oi[4];
#pragma unroll
    for (int q = 0; q < 4; ++q) {
      os[q] = __shfl_xor(ts[q], mask);
      oi[q] = __shfl_xor(ti[q], mask);
    }
#pragma unroll
    for (int q = 0; q < 4; ++q) ins4(os[q], oi[q], ts, ti);
  }
  if (fq == 0) {
    const int b = w * 16 + fr;
    const size_t base = ((size_t)b * NCHUNK + blockIdx.x) * 4;
#pragma unroll
    for (int q = 0; q < 4; ++q) { cand_s[base + q] = ts[q]; cand_i[base + q] = ti[q]; }
  }
}

// ---------------------------------------------------------------- merge + rescore + fuse + policy heads (fused)
__global__ __launch_bounds__(256)
void topk_heads(const float* __restrict__ cand_s, const int* __restrict__ cand_i,
                const float* __restrict__ bank, const float* __restrict__ vals,
                const float* __restrict__ rnorm, const float* __restrict__ r0,
                const float* __restrict__ Wc, const float* __restrict__ bc,
                const float* __restrict__ Wd, const float* __restrict__ bd,
                const float* __restrict__ Wsw, const float* __restrict__ bsw,
                const float* __restrict__ Wv, const float* __restrict__ bv,
                float* __restrict__ out) {
  const int b = blockIdx.x, t = threadIdx.x;
  __shared__ float rnL[256];
  __shared__ float ss[2048];
  __shared__ int   si[2048];
  __shared__ int   g8[8];
  __shared__ float sc8[8];
  __shared__ int   gidx[3];
  __shared__ float rl[256];
  __shared__ float red[256];
  __shared__ float hd[8];

  rnL[t] = rnorm[b * 256 + t];

  float ts[8]; int ti[8];
#pragma unroll
  for (int q = 0; q < 8; ++q) { ts[q] = -INFINITY; ti[q] = 0x7fffff00 + t * 8 + q; }
  const int n = NCHUNK * 4;
  const size_t base = (size_t)b * n;
  for (int c = t; c < n; c += 256) ins8(cand_s[base + c], cand_i[base + c], ts, ti);
#pragma unroll
  for (int q = 0; q < 8; ++q) { ss[t * 8 + q] = ts[q]; si[t * 8 + q] = ti[q]; }
  __syncthreads();

  if (t < 64) {
    float ms[8]; int mi[8];
#pragma unroll
    for (int q = 0; q < 8; ++q) { ms[q] = -INFINITY; mi[q] = 0x7ffffe00 + t * 8 + q; }
    for (int c = t * 32; c < t * 32 + 32; ++c) ins8(ss[c], si[c], ms, mi);
#pragma unroll
    for (int mask = 1; mask < 64; mask <<= 1) {
      float os[8]; int oi[8];
#pragma unroll
      for (int q = 0; q < 8; ++q) { os[q] = __shfl_xor(ms[q], mask); oi[q] = __shfl_xor(mi[q], mask); }
#pragma unroll
      for (int q = 0; q < 8; ++q) ins8(os[q], oi[q], ms, mi);
    }
    if (t == 0) {
#pragma unroll
      for (int q = 0; q < 8; ++q) g8[q] = mi[q];
    }
  }
  __syncthreads();

  {
    const int c = t >> 5, g = t & 31;
    const int id = g8[c];
    float ssq = 0.0f, dt = 0.0f;
    if (id < M_TOT) {
      const float4* bp = reinterpret_cast<const float4*>(bank + (size_t)id * 256);
      const float4 x0 = bp[g * 2], x1 = bp[g * 2 + 1];
      const float4 r0v = *reinterpret_cast<const float4*>(&rnL[g * 8]);
      const float4 r1v = *reinterpret_cast<const float4*>(&rnL[g * 8 + 4]);
      ssq = x0.x*x0.x + x0.y*x0.y + x0.z*x0.z + x0.w*x0.w +
            x1.x*x1.x + x1.y*x1.y + x1.z*x1.z + x1.w*x1.w;
      dt  = x0.x*r0v.x + x0.y*r0v.y + x0.z*r0v.z + x0.w*r0v.w +
            x1.x*r1v.x + x1.y*r1v.y + x1.z*r1v.z + x1.w*r1v.w;
    }
#pragma unroll
    for (int mask = 1; mask < 32; mask <<= 1) { ssq += __shfl_xor(ssq, mask); dt += __shfl_xor(dt, mask); }
    if (g == 0)
      sc8[c] = (id < M_TOT)
                 ? dt * (1.0f / fmaxf(sqrtf(ssq), 1e-12f)) * (vals[id] + 1e-8f)
                 : -INFINITY;
  }
  __syncthreads();

  if (t == 0) {
    float gs[3] = {-INFINITY, -INFINITY, -INFINITY};
    int gi[3] = {0x7fffffff, 0x7ffffffe, 0x7ffffffd};
#pragma unroll
    for (int q = 0; q < 8; ++q) ins3(sc8[q], g8[q], gs, gi);
    gidx[0] = gi[0]; gidx[1] = gi[1]; gidx[2] = gi[2];
  }
  __syncthreads();

  {
    const int i0 = gidx[0], i1 = gidx[1], i2 = gidx[2];
    const float retr = (bank[(size_t)i0 * 256 + t] + bank[(size_t)i1 * 256 + t] +
                        bank[(size_t)i2 * 256 + t]) / 3.0f;
    rl[t] = 0.5f * r0[b * 256 + t] + 0.5f * retr;
  }
  __syncthreads();

  float y = bd[t];
#pragma unroll 8
  for (int k = 0; k < 256; ++k) y += rl[k] * Wd[k * 256 + t];
  red[t] = y * y;
  if (t < 4) {
    float a;
    if (t == 0) { a = bc[0]; for (int k = 0; k < 256; ++k) a += rl[k] * Wc[2 * k]; }
    else if (t == 1) { a = bc[1]; for (int k = 0; k < 256; ++k) a += rl[k] * Wc[2 * k + 1]; }
    else if (t == 2) { a = bsw[0]; for (int k = 0; k < 256; ++k) a += rl[k] * Wsw[k]; }
    else { a = bv[0]; for (int k = 0; k < 256; ++k) a += rl[k] * Wv[k]; }
    hd[t] = a;
  }
  __syncthreads();
  for (int s = 128; s > 0; s >>= 1) { if (t < s) red[t] += red[t + s]; __syncthreads(); }
  const float dirn = y / fmaxf(sqrtf(red[0]), 1e-12f);
  if (t == 0) {
    const float l0 = hd[0], l1 = hd[1];
    uint32_t a0, a1, c0, c1;
    threefry2x32(0u, 1u, 0u, (uint32_t)(2 * b), a0, a1);
    threefry2x32(0u, 1u, 0u, (uint32_t)(2 * b + 1), c0, c1);
    const float g0 = gumbel_from_bits(a0 ^ a1);
    const float g1 = gumbel_from_bits(c0 ^ c1);
    const int act = (l1 + g1 > l0 + g0) ? 1 : 0;
    const float mx = fmaxf(l0, l1);
    const float lse = mx + logf(expf(l0 - mx) + expf(l1 - mx));
    const float lp0 = l0 - lse, lp1 = l1 - lse;
    out[OFF_ACT + b] = (float)act;
    out[OFF_LP + b] = act ? lp1 : lp0;
    out[OFF_VAL + b] = hd[3];
    out[OFF_ENT + b] = -(expf(lp0) * lp0 + expf(lp1) * lp1);
    hd[4] = 2.0f / (1.0f + expf(-hd[2]));
  }
  __syncthreads();
  out[OFF_POS + b * 256 + t] = rl[t] + hd[4] * dirn;
}

// ---------------------------------------------------------------- launch
extern "C" void kernel_launch(void* const* d_in, const int* in_sizes, int n_in,
                              void* d_out, int out_size, void* d_ws, size_t ws_size,
                              hipStream_t stream) {
  const float* state = (const float*)d_in[0];
  const float* bank  = (const float*)d_in[1];
  const float* vals  = (const float*)d_in[2];
  const float* W1  = (const float*)d_in[3];
  const float* b1  = (const float*)d_in[4];
  const float* W2  = (const float*)d_in[5];
  const float* b2  = (const float*)d_in[6];
  const float* Wc  = (const float*)d_in[7];
  const float* bc  = (const float*)d_in[8];
  const float* Wd  = (const float*)d_in[9];
  const float* bd  = (const float*)d_in[10];
  const float* Wsw = (const float*)d_in[11];
  const float* bsw = (const float*)d_in[12];
  const float* Wv  = (const float*)d_in[13];
  const float* bv  = (const float*)d_in[14];
  const float* T1w = (const float*)d_in[15];
  const float* t1b = (const float*)d_in[16];
  const float* T2w = (const float*)d_in[17];
  const float* t2b = (const float*)d_in[18];
  float* out = (float*)d_out;
  float* ws = (float*)d_ws;

  // workspace layout (floats). regA (2,097,152) holds W1 partials (8x131072)
  // and later T2 partials (4x524288); cs/ci overlap its head (dead interval).
  float* regA = ws;                   // 2,097,152
  float* cs   = ws;                   // 250,368 (128*489*4)  [overlaps regA]
  int*   ci   = (int*)(ws + 250368);  // 250,368              [overlaps regA]
  float* h1   = ws + 2097152;         // 131072
  float* regC = ws + 2228224;         // 524,288 (W2 partials 8x32768 / T1 partials 4x131072)
  float* r0   = ws + 2752512;         // 32768
  float* rnm  = ws + 2785280;         // 32768
  float* h2   = ws + 2818048;         // 131072
  uint32_t* rnbf = (uint32_t*)(ws + 2949120);   // 16,384 u32 (bf16 rnorm)

  // state_projection: H -> H/4 (relu) -> R
  gemm_tile<<<dim3(16, 2, 8), 256, 0, stream>>>(state, W1, regA, 128, 1024, 4096, 512);
  combine_z<8, true><<<512, 256, 0, stream>>>(regA, b1, h1, 131072, 1023);
  gemm_tile<<<dim3(4, 2, 8), 256, 0, stream>>>(h1, W2, regC, 128, 256, 1024, 128);
  combine_r0<<<128, 256, 0, stream>>>(regC, b2, r0, rnm, rnbf);
  // retrieval: single-pass fused sims (register-staged, max occupancy)
  sims_fused<<<NCHUNK, 512, 0, stream>>>(rnbf, bank, vals, cs, ci);
  topk_heads<<<128, 256, 0, stream>>>(cs, ci, bank, vals, rnm, r0,
                                      Wc, bc, Wd, bd, Wsw, bsw, Wv, bv, out);
  // thought_projection: R -> H/4 (relu) -> H  (K-split for parallelism)
  gemm_tile<<<dim3(16, 2, 4), 256, 0, stream>>>(out + OFF_POS, T1w, regC, 128, 1024, 256, 64);
  combine_z<4, true><<<512, 256, 0, stream>>>(regC, t1b, h2, 131072, 1023);
  gemm_tile<<<dim3(64, 2, 4), 256, 0, stream>>>(h2, T2w, regA, 128, 4096, 1024, 256);
  combine_z<4, false><<<2048, 256, 0, stream>>>(regA, t2b, out + OFF_LATENT, 524288, 4095);
}

// Round 20
// 316.412 us; speedup vs baseline: 1.5914x; 1.0042x over previous
//
#include <hip/hip_runtime.h>
#include <hip/hip_bf16.h>
#include <math.h>
#include <stdint.h>

// Problem constants (CoconutPPO): B=128, H=4096, R=256, M=500000, K=3
#define BB 128
#define HH 4096
#define RR 256
#define M_TOT 500000
#define CHUNK 1024
#define NCHUNK ((M_TOT + CHUNK - 1) / CHUNK)   // 489
#define NSUB (CHUNK / 16)                      // 64 subs of 16 rows
#define TINYF 1.17549435e-38f

// d_out layout (floats, concatenated in return order)
#define OFF_LATENT 0
#define OFF_POS    524288
#define OFF_ACT    557056
#define OFF_LP     557184
#define OFF_VAL    557312
#define OFF_ENT    557440

typedef __attribute__((ext_vector_type(8))) short bf16x8;
typedef __attribute__((ext_vector_type(4))) float f32x4;

// ---------------------------------------------------------------- helpers
__device__ __forceinline__ bool better(float a, int ia, float b, int ib) {
  return a > b || (a == b && ia < ib);
}
__device__ __forceinline__ void ins4_nd(float s, int id, float (&vs)[4], int (&vi)[4]) {
  if (better(s, id, vs[3], vi[3])) {
    vs[3] = s; vi[3] = id;
    if (better(vs[3], vi[3], vs[2], vi[2])) { float a=vs[3]; vs[3]=vs[2]; vs[2]=a; int x=vi[3]; vi[3]=vi[2]; vi[2]=x; }
    if (better(vs[2], vi[2], vs[1], vi[1])) { float a=vs[2]; vs[2]=vs[1]; vs[1]=a; int x=vi[2]; vi[2]=vi[1]; vi[1]=x; }
    if (better(vs[1], vi[1], vs[0], vi[0])) { float a=vs[1]; vs[1]=vs[0]; vs[0]=a; int x=vi[1]; vi[1]=vi[0]; vi[0]=x; }
  }
}
__device__ __forceinline__ void ins4(float s, int id, float (&vs)[4], int (&vi)[4]) {
  if (id == vi[0] || id == vi[1] || id == vi[2] || id == vi[3]) return;
  ins4_nd(s, id, vs, vi);
}
__device__ __forceinline__ void ins3(float s, int id, float (&vs)[3], int (&vi)[3]) {
  if (id == vi[0] || id == vi[1] || id == vi[2]) return;
  if (better(s, id, vs[2], vi[2])) {
    vs[2] = s; vi[2] = id;
    if (better(vs[2], vi[2], vs[1], vi[1])) { float a=vs[2]; vs[2]=vs[1]; vs[1]=a; int x=vi[2]; vi[2]=vi[1]; vi[1]=x; }
    if (better(vs[1], vi[1], vs[0], vi[0])) { float a=vs[1]; vs[1]=vs[0]; vs[0]=a; int x=vi[1]; vi[1]=vi[0]; vi[0]=x; }
  }
}
__device__ __forceinline__ void ins8(float s, int id, float (&vs)[8], int (&vi)[8]) {
#pragma unroll
  for (int q = 0; q < 8; ++q) if (id == vi[q]) return;
  if (!better(s, id, vs[7], vi[7])) return;
  vs[7] = s; vi[7] = id;
#pragma unroll
  for (int q = 7; q > 0; --q)
    if (better(vs[q], vi[q], vs[q-1], vi[q-1])) {
      float a = vs[q]; vs[q] = vs[q-1]; vs[q-1] = a;
      int x = vi[q]; vi[q] = vi[q-1]; vi[q-1] = x;
    }
}

// RNE f32 -> bf16 (bit arithmetic; matches hardware/NumPy RNE)
__device__ __forceinline__ uint32_t rne_u(float x) {
  uint32_t u = __float_as_uint(x);
  return (u + 0x7fffu + ((u >> 16) & 1u)) >> 16;
}
__device__ __forceinline__ uint32_t pk_bf16(float lo, float hi) {
  return rne_u(lo) | (rne_u(hi) << 16);
}

// async global->LDS (wave-uniform LDS base, per-lane global source)
__device__ __forceinline__ void load_lds4(const void* g, void* l) {
  __builtin_amdgcn_global_load_lds((const __attribute__((address_space(1))) void*)g,
                                   (__attribute__((address_space(3))) void*)l, 4, 0, 0);
}

#define TF_ROUND(r) { x0 += x1; x1 = (x1 << (r)) | (x1 >> (32 - (r))); x1 ^= x0; }
__device__ __forceinline__ void threefry2x32(uint32_t k0, uint32_t k1,
                                             uint32_t x0, uint32_t x1,
                                             uint32_t& o0, uint32_t& o1) {
  const uint32_t ks2 = k0 ^ k1 ^ 0x1BD11BDAu;
  x0 += k0; x1 += k1;
  TF_ROUND(13) TF_ROUND(15) TF_ROUND(26) TF_ROUND(6)
  x0 += k1; x1 += ks2 + 1u;
  TF_ROUND(17) TF_ROUND(29) TF_ROUND(16) TF_ROUND(24)
  x0 += ks2; x1 += k0 + 2u;
  TF_ROUND(13) TF_ROUND(15) TF_ROUND(26) TF_ROUND(6)
  x0 += k0; x1 += k1 + 3u;
  TF_ROUND(17) TF_ROUND(29) TF_ROUND(16) TF_ROUND(24)
  x0 += k1; x1 += ks2 + 4u;
  TF_ROUND(13) TF_ROUND(15) TF_ROUND(26) TF_ROUND(6)
  x0 += ks2; x1 += k0 + 5u;
  o0 = x0; o1 = x1;
}

__device__ __forceinline__ float gumbel_from_bits(uint32_t bits) {
  const uint32_t fb = (bits >> 9) | 0x3f800000u;
  const float fl = __uint_as_float(fb) - 1.0f;
  const float u = fmaxf(TINYF, fl * (1.0f - TINYF) + TINYF);
  return -logf(-logf(u));
}

// ---------------------------------------------------------------- generic fp32 GEMM (partial slabs)
__global__ __launch_bounds__(256)
void gemm_tile(const float* __restrict__ A, const float* __restrict__ Bw,
               float* __restrict__ C, int Mr, int Nc, int K, int klen) {
  __shared__ float As[16][68];
  __shared__ float Bs[16][68];
  const int col0 = blockIdx.x * 64;
  const int row0 = blockIdx.y * 64;
  const int k0 = blockIdx.z * klen;
  const int t = threadIdx.x;
  const int tc = t & 15, tr = t >> 4;
  float acc[4][4] = {};
  for (int kk = k0; kk < k0 + klen; kk += 16) {
    {
      const int r = t >> 2, c4 = (t & 3) << 2;
      const float4 v = *reinterpret_cast<const float4*>(A + (size_t)(row0 + r) * K + kk + c4);
      As[c4 + 0][r] = v.x; As[c4 + 1][r] = v.y; As[c4 + 2][r] = v.z; As[c4 + 3][r] = v.w;
    }
    {
      const int kr = t >> 4, c4 = (t & 15) << 2;
      const float4 v = *reinterpret_cast<const float4*>(Bw + (size_t)(kk + kr) * Nc + col0 + c4);
      *reinterpret_cast<float4*>(&Bs[kr][c4]) = v;
    }
    __syncthreads();
#pragma unroll
    for (int k = 0; k < 16; ++k) {
      const float4 a4 = *reinterpret_cast<const float4*>(&As[k][tr * 4]);
      const float4 b4 = *reinterpret_cast<const float4*>(&Bs[k][tc * 4]);
      float a[4] = {a4.x, a4.y, a4.z, a4.w};
      float b[4] = {b4.x, b4.y, b4.z, b4.w};
#pragma unroll
      for (int i = 0; i < 4; ++i)
#pragma unroll
        for (int j = 0; j < 4; ++j) acc[i][j] += a[i] * b[j];
    }
    __syncthreads();
  }
  float* Cp = C + (size_t)blockIdx.z * Mr * Nc;
#pragma unroll
  for (int i = 0; i < 4; ++i) {
    const int row = row0 + tr * 4 + i;
#pragma unroll
    for (int j = 0; j < 4; ++j) {
      Cp[(size_t)row * Nc + col0 + tc * 4 + j] = acc[i][j];
    }
  }
}

// ---------------------------------------------------------------- combines
template<int Z, bool RELU>
__global__ void combine_z(const float* __restrict__ src, const float* __restrict__ bias,
                          float* __restrict__ dst, int total, int mask) {
  const int i = blockIdx.x * 256 + threadIdx.x;
  float v = bias[i & mask];
#pragma unroll
  for (int z = 0; z < Z; ++z) v += src[(size_t)z * total + i];
  dst[i] = RELU ? fmaxf(v, 0.0f) : v;
}

__global__ __launch_bounds__(256)
void combine_r0(const float* __restrict__ r0p, const float* __restrict__ b2,
                float* __restrict__ r0, float* __restrict__ rnorm,
                uint32_t* __restrict__ rnbf) {
  const int b = blockIdx.x, t = threadIdx.x;
  __shared__ float red[256];
  __shared__ float vtmp[256];
  float v = b2[t];
#pragma unroll
  for (int z = 0; z < 8; ++z) v += r0p[z * 32768 + b * 256 + t];
  r0[b * 256 + t] = v;
  red[t] = v * v;
  __syncthreads();
  for (int s = 128; s > 0; s >>= 1) { if (t < s) red[t] += red[t + s]; __syncthreads(); }
  const float inv = 1.0f / fmaxf(sqrtf(red[0]), 1e-12f);
  const float vn = v * inv;
  rnorm[b * 256 + t] = vn;
  vtmp[t] = vn;
  __syncthreads();
  if (t < 128) rnbf[b * 128 + t] = pk_bf16(vtmp[2 * t], vtmp[2 * t + 1]);
}

// ---------------------------------------------------------------- FUSED MFMA sims (register-staged, 1 barrier / 2 subs)
// 512 thr / 8 waves, 36 KB LDS. 64 subs of 16 rows; fp32 rows staged in
// REGISTERS (2 named buffer pairs pA/pB, 2 subs in flight; compiler inserts
// vmcnt waits at consumption). tB has 4 buffers (2 pairs): per iteration,
// convert subs s2,s2+1 into pair p, refill registers, ONE lgkmcnt+barrier,
// then both MFMAs -- iteration i+1 writes pair p^1 whose last reads (iter
// i-1) are ordered by barrier(i) + each wave's own pre-barrier lgkmcnt(0).
// Halves barrier count vs round 19 (32/chunk); vmcnt never drained mid-loop.
__global__ __launch_bounds__(512, 4)
void sims_fused(const uint32_t* __restrict__ rnbf, const float* __restrict__ bank,
                const float* __restrict__ vals, float* __restrict__ cand_s,
                int* __restrict__ cand_i) {
  __shared__ __align__(16) unsigned short tB[4][16 * 256];  // 4 x 8 KB
  __shared__ float valsL[CHUNK];                            // 4 KB

  const int t = threadIdx.x;
  const int lane = t & 63;
  const int w = t >> 6;            // wave 0..7 -> batch rows w*16..w*16+15
  const int fr = lane & 15;
  const int fq = lane >> 4;        // 0..3 (k-group)
  const int cbase = blockIdx.x * CHUNK;

  // ---- B-frags (one 16-row batch set per wave) from bf16 rnorm
  bf16x8 Bf[8];
  {
    const uint4* rp = reinterpret_cast<const uint4*>(rnbf + (size_t)(w * 16 + fr) * 128);
#pragma unroll
    for (int ks = 0; ks < 8; ++ks) {
      uint4 u = rp[ks * 4 + fq];
      Bf[ks] = *reinterpret_cast<bf16x8*>(&u);
    }
  }

  float ts[4]; int ti[4];
#pragma unroll
  for (int q = 0; q < 4; ++q) { ts[q] = -INFINITY; ti[q] = 0x7ffffff0 + q; }

  float4 pA0, pA1, pB0, pB1;       // register staging (2 subs in flight)

  auto loadrow = [&](int m) -> float4 {
    if (m > M_TOT - 1) m = M_TOT - 1;          // clamp: row skipped in epilogue
    return *reinterpret_cast<const float4*>(bank + (size_t)m * 256 + lane * 4);
  };
  auto issueA = [&](int s) {
    pA0 = loadrow(cbase + s * 16 + w * 2);
    pA1 = loadrow(cbase + s * 16 + w * 2 + 1);
  };
  auto issueB = [&](int s) {
    pB0 = loadrow(cbase + s * 16 + w * 2);
    pB1 = loadrow(cbase + s * 16 + w * 2 + 1);
  };
  auto convrow = [&](const float4 v, int s, int r, unsigned short* dst) {
    float ssq = v.x * v.x + v.y * v.y + v.z * v.z + v.w * v.w;
#pragma unroll
    for (int msk = 1; msk < 64; msk <<= 1) ssq += __shfl_xor(ssq, msk);
    const float vv = valsL[s * 16 + r];
    const float wsc = (vv + 1e-8f) / fmaxf(sqrtf(ssq), 1e-12f);
    uint2 p;
    p.x = pk_bf16(v.x * wsc, v.y * wsc);
    p.y = pk_bf16(v.z * wsc, v.w * wsc);
    const int c = lane >> 1, h = lane & 1;
    *reinterpret_cast<uint2*>(
        reinterpret_cast<char*>(dst) + r * 512 + (((c ^ (r & 7)) << 4) + h * 8)) = p;
  };
  auto mfma_epi = [&](int s, const unsigned short* tc) {
    f32x4 acc = (f32x4){0.f, 0.f, 0.f, 0.f};
#pragma unroll
    for (int ks = 0; ks < 8; ++ks) {
      const int kc = ks * 4 + fq;
      const bf16x8 a = *reinterpret_cast<const bf16x8*>(
          tc + fr * 256 + ((kc ^ (fr & 7)) << 3));
      acc = __builtin_amdgcn_mfma_f32_16x16x32_bf16(a, Bf[ks], acc, 0, 0, 0);
    }
    const int m_base = cbase + s * 16;
#pragma unroll
    for (int j = 0; j < 4; ++j) {
      const int mm = m_base + fq * 4 + j;
      if (mm < M_TOT) ins4_nd(acc[j], mm, ts, ti);
    }
  };

  // ---- prologue: vals -> LDS (2 gload_lds4/wave), subs 0,1 -> registers
#pragma unroll
  for (int j = 0; j < 2; ++j) {
    const int seg = w * 2 + j;                   // 0..15, 64 floats each
    int mi = cbase + seg * 64 + lane;
    if (mi > M_TOT - 1) mi = M_TOT - 1;
    load_lds4(vals + mi, reinterpret_cast<char*>(valsL) + seg * 256);
  }
  issueA(0); issueB(1);
  asm volatile("s_waitcnt vmcnt(0)" ::: "memory");   // one-time full drain: valsL + pA/pB
  __builtin_amdgcn_sched_barrier(0);
  __builtin_amdgcn_s_barrier();                      // valsL visible

  for (int s2 = 0; s2 < NSUB; s2 += 2) {
    const int pr = (s2 >> 1) & 1;                // buffer pair 0 or 1
    unsigned short* t0 = tB[pr * 2];
    unsigned short* t1 = tB[pr * 2 + 1];
    // ---- convert both staged subs into this pair
    convrow(pA0, s2, w * 2, t0);
    convrow(pA1, s2, w * 2 + 1, t0);
    convrow(pB0, s2 + 1, w * 2, t1);
    convrow(pB1, s2 + 1, w * 2 + 1, t1);
    // ---- refill registers for subs s2+2, s2+3 (land under MFMA + next convert)
    if (s2 + 2 < NSUB) issueA(s2 + 2);
    if (s2 + 3 < NSUB) issueB(s2 + 3);
    asm volatile("s_waitcnt lgkmcnt(0)" ::: "memory");
    __builtin_amdgcn_sched_barrier(0);
    __builtin_amdgcn_s_barrier();                // pair visible to all waves
    mfma_epi(s2, t0);
    mfma_epi(s2 + 1, t1);
  }

  // merge the 4 fq-lane groups sharing each batch row (snapshot butterfly)
#pragma unroll
  for (int mask = 16; mask < 64; mask <<= 1) {
    float os[4]; int oi[4];
#pragma unroll
    for (int q = 0; q < 4; ++q) {
      os[q] = __shfl_xor(ts[q], mask);
      oi[q] = __shfl_xor(ti[q], mask);
    }
#pragma unroll
    for (int q = 0; q < 4; ++q) ins4(os[q], oi[q], ts, ti);
  }
  if (fq == 0) {
    const int b = w * 16 + fr;
    const size_t base = ((size_t)b * NCHUNK + blockIdx.x) * 4;
#pragma unroll
    for (int q = 0; q < 4; ++q) { cand_s[base + q] = ts[q]; cand_i[base + q] = ti[q]; }
  }
}

// ---------------------------------------------------------------- merge + rescore + fuse + policy heads (fused)
__global__ __launch_bounds__(256)
void topk_heads(const float* __restrict__ cand_s, const int* __restrict__ cand_i,
                const float* __restrict__ bank, const float* __restrict__ vals,
                const float* __restrict__ rnorm, const float* __restrict__ r0,
                const float* __restrict__ Wc, const float* __restrict__ bc,
                const float* __restrict__ Wd, const float* __restrict__ bd,
                const float* __restrict__ Wsw, const float* __restrict__ bsw,
                const float* __restrict__ Wv, const float* __restrict__ bv,
                float* __restrict__ out) {
  const int b = blockIdx.x, t = threadIdx.x;
  __shared__ float rnL[256];
  __shared__ float ss[2048];
  __shared__ int   si[2048];
  __shared__ int   g8[8];
  __shared__ float sc8[8];
  __shared__ int   gidx[3];
  __shared__ float rl[256];
  __shared__ float red[256];
  __shared__ float hd[8];

  rnL[t] = rnorm[b * 256 + t];

  float ts[8]; int ti[8];
#pragma unroll
  for (int q = 0; q < 8; ++q) { ts[q] = -INFINITY; ti[q] = 0x7fffff00 + t * 8 + q; }
  const int n = NCHUNK * 4;
  const size_t base = (size_t)b * n;
  for (int c = t; c < n; c += 256) ins8(cand_s[base + c], cand_i[base + c], ts, ti);
#pragma unroll
  for (int q = 0; q < 8; ++q) { ss[t * 8 + q] = ts[q]; si[t * 8 + q] = ti[q]; }
  __syncthreads();

  if (t < 64) {
    float ms[8]; int mi[8];
#pragma unroll
    for (int q = 0; q < 8; ++q) { ms[q] = -INFINITY; mi[q] = 0x7ffffe00 + t * 8 + q; }
    for (int c = t * 32; c < t * 32 + 32; ++c) ins8(ss[c], si[c], ms, mi);
#pragma unroll
    for (int mask = 1; mask < 64; mask <<= 1) {
      float os[8]; int oi[8];
#pragma unroll
      for (int q = 0; q < 8; ++q) { os[q] = __shfl_xor(ms[q], mask); oi[q] = __shfl_xor(mi[q], mask); }
#pragma unroll
      for (int q = 0; q < 8; ++q) ins8(os[q], oi[q], ms, mi);
    }
    if (t == 0) {
#pragma unroll
      for (int q = 0; q < 8; ++q) g8[q] = mi[q];
    }
  }
  __syncthreads();

  {
    const int c = t >> 5, g = t & 31;
    const int id = g8[c];
    float ssq = 0.0f, dt = 0.0f;
    if (id < M_TOT) {
      const float4* bp = reinterpret_cast<const float4*>(bank + (size_t)id * 256);
      const float4 x0 = bp[g * 2], x1 = bp[g * 2 + 1];
      const float4 r0v = *reinterpret_cast<const float4*>(&rnL[g * 8]);
      const float4 r1v = *reinterpret_cast<const float4*>(&rnL[g * 8 + 4]);
      ssq = x0.x*x0.x + x0.y*x0.y + x0.z*x0.z + x0.w*x0.w +
            x1.x*x1.x + x1.y*x1.y + x1.z*x1.z + x1.w*x1.w;
      dt  = x0.x*r0v.x + x0.y*r0v.y + x0.z*r0v.z + x0.w*r0v.w +
            x1.x*r1v.x + x1.y*r1v.y + x1.z*r1v.z + x1.w*r1v.w;
    }
#pragma unroll
    for (int mask = 1; mask < 32; mask <<= 1) { ssq += __shfl_xor(ssq, mask); dt += __shfl_xor(dt, mask); }
    if (g == 0)
      sc8[c] = (id < M_TOT)
                 ? dt * (1.0f / fmaxf(sqrtf(ssq), 1e-12f)) * (vals[id] + 1e-8f)
                 : -INFINITY;
  }
  __syncthreads();

  if (t == 0) {
    float gs[3] = {-INFINITY, -INFINITY, -INFINITY};
    int gi[3] = {0x7fffffff, 0x7ffffffe, 0x7ffffffd};
#pragma unroll
    for (int q = 0; q < 8; ++q) ins3(sc8[q], g8[q], gs, gi);
    gidx[0] = gi[0]; gidx[1] = gi[1]; gidx[2] = gi[2];
  }
  __syncthreads();

  {
    const int i0 = gidx[0], i1 = gidx[1], i2 = gidx[2];
    const float retr = (bank[(size_t)i0 * 256 + t] + bank[(size_t)i1 * 256 + t] +
                        bank[(size_t)i2 * 256 + t]) / 3.0f;
    rl[t] = 0.5f * r0[b * 256 + t] + 0.5f * retr;
  }
  __syncthreads();

  float y = bd[t];
#pragma unroll 8
  for (int k = 0; k < 256; ++k) y += rl[k] * Wd[k * 256 + t];
  red[t] = y * y;
  if (t < 4) {
    float a;
    if (t == 0) { a = bc[0]; for (int k = 0; k < 256; ++k) a += rl[k] * Wc[2 * k]; }
    else if (t == 1) { a = bc[1]; for (int k = 0; k < 256; ++k) a += rl[k] * Wc[2 * k + 1]; }
    else if (t == 2) { a = bsw[0]; for (int k = 0; k < 256; ++k) a += rl[k] * Wsw[k]; }
    else { a = bv[0]; for (int k = 0; k < 256; ++k) a += rl[k] * Wv[k]; }
    hd[t] = a;
  }
  __syncthreads();
  for (int s = 128; s > 0; s >>= 1) { if (t < s) red[t] += red[t + s]; __syncthreads(); }
  const float dirn = y / fmaxf(sqrtf(red[0]), 1e-12f);
  if (t == 0) {
    const float l0 = hd[0], l1 = hd[1];
    uint32_t a0, a1, c0, c1;
    threefry2x32(0u, 1u, 0u, (uint32_t)(2 * b), a0, a1);
    threefry2x32(0u, 1u, 0u, (uint32_t)(2 * b + 1), c0, c1);
    const float g0 = gumbel_from_bits(a0 ^ a1);
    const float g1 = gumbel_from_bits(c0 ^ c1);
    const int act = (l1 + g1 > l0 + g0) ? 1 : 0;
    const float mx = fmaxf(l0, l1);
    const float lse = mx + logf(expf(l0 - mx) + expf(l1 - mx));
    const float lp0 = l0 - lse, lp1 = l1 - lse;
    out[OFF_ACT + b] = (float)act;
    out[OFF_LP + b] = act ? lp1 : lp0;
    out[OFF_VAL + b] = hd[3];
    out[OFF_ENT + b] = -(expf(lp0) * lp0 + expf(lp1) * lp1);
    hd[4] = 2.0f / (1.0f + expf(-hd[2]));
  }
  __syncthreads();
  out[OFF_POS + b * 256 + t] = rl[t] + hd[4] * dirn;
}

// ---------------------------------------------------------------- launch
extern "C" void kernel_launch(void* const* d_in, const int* in_sizes, int n_in,
                              void* d_out, int out_size, void* d_ws, size_t ws_size,
                              hipStream_t stream) {
  const float* state = (const float*)d_in[0];
  const float* bank  = (const float*)d_in[1];
  const float* vals  = (const float*)d_in[2];
  const float* W1  = (const float*)d_in[3];
  const float* b1  = (const float*)d_in[4];
  const float* W2  = (const float*)d_in[5];
  const float* b2  = (const float*)d_in[6];
  const float* Wc  = (const float*)d_in[7];
  const float* bc  = (const float*)d_in[8];
  const float* Wd  = (const float*)d_in[9];
  const float* bd  = (const float*)d_in[10];
  const float* Wsw = (const float*)d_in[11];
  const float* bsw = (const float*)d_in[12];
  const float* Wv  = (const float*)d_in[13];
  const float* bv  = (const float*)d_in[14];
  const float* T1w = (const float*)d_in[15];
  const float* t1b = (const float*)d_in[16];
  const float* T2w = (const float*)d_in[17];
  const float* t2b = (const float*)d_in[18];
  float* out = (float*)d_out;
  float* ws = (float*)d_ws;

  // workspace layout (floats). regA (2,097,152) holds W1 partials (8x131072)
  // and later T2 partials (4x524288); cs/ci overlap its head (dead interval).
  float* regA = ws;                   // 2,097,152
  float* cs   = ws;                   // 250,368 (128*489*4)  [overlaps regA]
  int*   ci   = (int*)(ws + 250368);  // 250,368              [overlaps regA]
  float* h1   = ws + 2097152;         // 131072
  float* regC = ws + 2228224;         // 524,288 (W2 partials 8x32768 / T1 partials 4x131072)
  float* r0   = ws + 2752512;         // 32768
  float* rnm  = ws + 2785280;         // 32768
  float* h2   = ws + 2818048;         // 131072
  uint32_t* rnbf = (uint32_t*)(ws + 2949120);   // 16,384 u32 (bf16 rnorm)

  // state_projection: H -> H/4 (relu) -> R
  gemm_tile<<<dim3(16, 2, 8), 256, 0, stream>>>(state, W1, regA, 128, 1024, 4096, 512);
  combine_z<8, true><<<512, 256, 0, stream>>>(regA, b1, h1, 131072, 1023);
  gemm_tile<<<dim3(4, 2, 8), 256, 0, stream>>>(h1, W2, regC, 128, 256, 1024, 128);
  combine_r0<<<128, 256, 0, stream>>>(regC, b2, r0, rnm, rnbf);
  // retrieval: single-pass fused sims (register-staged, 1 barrier / 2 subs)
  sims_fused<<<NCHUNK, 512, 0, stream>>>(rnbf, bank, vals, cs, ci);
  topk_heads<<<128, 256, 0, stream>>>(cs, ci, bank, vals, rnm, r0,
                                      Wc, bc, Wd, bd, Wsw, bsw, Wv, bv, out);
  // thought_projection: R -> H/4 (relu) -> H  (K-split for parallelism)
  gemm_tile<<<dim3(16, 2, 4), 256, 0, stream>>>(out + OFF_POS, T1w, regC, 128, 1024, 256, 64);
  combine_z<4, true><<<512, 256, 0, stream>>>(regC, t1b, h2, 131072, 1023);
  gemm_tile<<<dim3(64, 2, 4), 256, 0, stream>>>(h2, T2w, regA, 128, 4096, 1024, 256);
  combine_z<4, false><<<2048, 256, 0, stream>>>(regA, t2b, out + OFF_LATENT, 524288, 4095);
}

// Round 21
// 306.341 us; speedup vs baseline: 1.6437x; 1.0329x over previous
//
#include <hip/hip_runtime.h>
#include <hip/hip_bf16.h>
#include <math.h>
#include <stdint.h>

// Problem constants (CoconutPPO): B=128, H=4096, R=256, M=500000, K=3
#define BB 128
#define HH 4096
#define RR 256
#define M_TOT 500000
#define CHUNK 1024
#define NCHUNK ((M_TOT + CHUNK - 1) / CHUNK)   // 489
#define NSUB (CHUNK / 16)                      // 64 subs of 16 rows
#define TINYF 1.17549435e-38f

// d_out layout (floats, concatenated in return order)
#define OFF_LATENT 0
#define OFF_POS    524288
#define OFF_ACT    557056
#define OFF_LP     557184
#define OFF_VAL    557312
#define OFF_ENT    557440

typedef __attribute__((ext_vector_type(8))) short bf16x8;
typedef __attribute__((ext_vector_type(4))) float f32x4;

// ---------------------------------------------------------------- helpers
__device__ __forceinline__ bool better(float a, int ia, float b, int ib) {
  return a > b || (a == b && ia < ib);
}
__device__ __forceinline__ void ins4_nd(float s, int id, float (&vs)[4], int (&vi)[4]) {
  if (better(s, id, vs[3], vi[3])) {
    vs[3] = s; vi[3] = id;
    if (better(vs[3], vi[3], vs[2], vi[2])) { float a=vs[3]; vs[3]=vs[2]; vs[2]=a; int x=vi[3]; vi[3]=vi[2]; vi[2]=x; }
    if (better(vs[2], vi[2], vs[1], vi[1])) { float a=vs[2]; vs[2]=vs[1]; vs[1]=a; int x=vi[2]; vi[2]=vi[1]; vi[1]=x; }
    if (better(vs[1], vi[1], vs[0], vi[0])) { float a=vs[1]; vs[1]=vs[0]; vs[0]=a; int x=vi[1]; vi[1]=vi[0]; vi[0]=x; }
  }
}
__device__ __forceinline__ void ins4(float s, int id, float (&vs)[4], int (&vi)[4]) {
  if (id == vi[0] || id == vi[1] || id == vi[2] || id == vi[3]) return;
  ins4_nd(s, id, vs, vi);
}
__device__ __forceinline__ void ins3(float s, int id, float (&vs)[3], int (&vi)[3]) {
  if (id == vi[0] || id == vi[1] || id == vi[2]) return;
  if (better(s, id, vs[2], vi[2])) {
    vs[2] = s; vi[2] = id;
    if (better(vs[2], vi[2], vs[1], vi[1])) { float a=vs[2]; vs[2]=vs[1]; vs[1]=a; int x=vi[2]; vi[2]=vi[1]; vi[1]=x; }
    if (better(vs[1], vi[1], vs[0], vi[0])) { float a=vs[1]; vs[1]=vs[0]; vs[0]=a; int x=vi[1]; vi[1]=vi[0]; vi[0]=x; }
  }
}
__device__ __forceinline__ void ins8(float s, int id, float (&vs)[8], int (&vi)[8]) {
#pragma unroll
  for (int q = 0; q < 8; ++q) if (id == vi[q]) return;
  if (!better(s, id, vs[7], vi[7])) return;
  vs[7] = s; vi[7] = id;
#pragma unroll
  for (int q = 7; q > 0; --q)
    if (better(vs[q], vi[q], vs[q-1], vi[q-1])) {
      float a = vs[q]; vs[q] = vs[q-1]; vs[q-1] = a;
      int x = vi[q]; vi[q] = vi[q-1]; vi[q-1] = x;
    }
}

// RNE f32 -> bf16 (bit arithmetic; matches hardware/NumPy RNE)
__device__ __forceinline__ uint32_t rne_u(float x) {
  uint32_t u = __float_as_uint(x);
  return (u + 0x7fffu + ((u >> 16) & 1u)) >> 16;
}
__device__ __forceinline__ uint32_t pk_bf16(float lo, float hi) {
  return rne_u(lo) | (rne_u(hi) << 16);
}

// async global->LDS (wave-uniform LDS base, per-lane global source)
__device__ __forceinline__ void load_lds4(const void* g, void* l) {
  __builtin_amdgcn_global_load_lds((const __attribute__((address_space(1))) void*)g,
                                   (__attribute__((address_space(3))) void*)l, 4, 0, 0);
}

#define TF_ROUND(r) { x0 += x1; x1 = (x1 << (r)) | (x1 >> (32 - (r))); x1 ^= x0; }
__device__ __forceinline__ void threefry2x32(uint32_t k0, uint32_t k1,
                                             uint32_t x0, uint32_t x1,
                                             uint32_t& o0, uint32_t& o1) {
  const uint32_t ks2 = k0 ^ k1 ^ 0x1BD11BDAu;
  x0 += k0; x1 += k1;
  TF_ROUND(13) TF_ROUND(15) TF_ROUND(26) TF_ROUND(6)
  x0 += k1; x1 += ks2 + 1u;
  TF_ROUND(17) TF_ROUND(29) TF_ROUND(16) TF_ROUND(24)
  x0 += ks2; x1 += k0 + 2u;
  TF_ROUND(13) TF_ROUND(15) TF_ROUND(26) TF_ROUND(6)
  x0 += k0; x1 += k1 + 3u;
  TF_ROUND(17) TF_ROUND(29) TF_ROUND(16) TF_ROUND(24)
  x0 += k1; x1 += ks2 + 4u;
  TF_ROUND(13) TF_ROUND(15) TF_ROUND(26) TF_ROUND(6)
  x0 += ks2; x1 += k0 + 5u;
  o0 = x0; o1 = x1;
}

__device__ __forceinline__ float gumbel_from_bits(uint32_t bits) {
  const uint32_t fb = (bits >> 9) | 0x3f800000u;
  const float fl = __uint_as_float(fb) - 1.0f;
  const float u = fmaxf(TINYF, fl * (1.0f - TINYF) + TINYF);
  return -logf(-logf(u));
}

// ---------------------------------------------------------------- generic fp32 GEMM (partial slabs)
__global__ __launch_bounds__(256)
void gemm_tile(const float* __restrict__ A, const float* __restrict__ Bw,
               float* __restrict__ C, int Mr, int Nc, int K, int klen) {
  __shared__ float As[16][68];
  __shared__ float Bs[16][68];
  const int col0 = blockIdx.x * 64;
  const int row0 = blockIdx.y * 64;
  const int k0 = blockIdx.z * klen;
  const int t = threadIdx.x;
  const int tc = t & 15, tr = t >> 4;
  float acc[4][4] = {};
  for (int kk = k0; kk < k0 + klen; kk += 16) {
    {
      const int r = t >> 2, c4 = (t & 3) << 2;
      const float4 v = *reinterpret_cast<const float4*>(A + (size_t)(row0 + r) * K + kk + c4);
      As[c4 + 0][r] = v.x; As[c4 + 1][r] = v.y; As[c4 + 2][r] = v.z; As[c4 + 3][r] = v.w;
    }
    {
      const int kr = t >> 4, c4 = (t & 15) << 2;
      const float4 v = *reinterpret_cast<const float4*>(Bw + (size_t)(kk + kr) * Nc + col0 + c4);
      *reinterpret_cast<float4*>(&Bs[kr][c4]) = v;
    }
    __syncthreads();
#pragma unroll
    for (int k = 0; k < 16; ++k) {
      const float4 a4 = *reinterpret_cast<const float4*>(&As[k][tr * 4]);
      const float4 b4 = *reinterpret_cast<const float4*>(&Bs[k][tc * 4]);
      float a[4] = {a4.x, a4.y, a4.z, a4.w};
      float b[4] = {b4.x, b4.y, b4.z, b4.w};
#pragma unroll
      for (int i = 0; i < 4; ++i)
#pragma unroll
        for (int j = 0; j < 4; ++j) acc[i][j] += a[i] * b[j];
    }
    __syncthreads();
  }
  float* Cp = C + (size_t)blockIdx.z * Mr * Nc;
#pragma unroll
  for (int i = 0; i < 4; ++i) {
    const int row = row0 + tr * 4 + i;
#pragma unroll
    for (int j = 0; j < 4; ++j) {
      Cp[(size_t)row * Nc + col0 + tc * 4 + j] = acc[i][j];
    }
  }
}

// ---------------------------------------------------------------- combines
template<int Z, bool RELU>
__global__ void combine_z(const float* __restrict__ src, const float* __restrict__ bias,
                          float* __restrict__ dst, int total, int mask) {
  const int i = blockIdx.x * 256 + threadIdx.x;
  float v = bias[i & mask];
#pragma unroll
  for (int z = 0; z < Z; ++z) v += src[(size_t)z * total + i];
  dst[i] = RELU ? fmaxf(v, 0.0f) : v;
}

__global__ __launch_bounds__(256)
void combine_r0(const float* __restrict__ r0p, const float* __restrict__ b2,
                float* __restrict__ r0, float* __restrict__ rnorm,
                uint32_t* __restrict__ rnbf) {
  const int b = blockIdx.x, t = threadIdx.x;
  __shared__ float red[256];
  __shared__ float vtmp[256];
  float v = b2[t];
#pragma unroll
  for (int z = 0; z < 8; ++z) v += r0p[z * 32768 + b * 256 + t];
  r0[b * 256 + t] = v;
  red[t] = v * v;
  __syncthreads();
  for (int s = 128; s > 0; s >>= 1) { if (t < s) red[t] += red[t + s]; __syncthreads(); }
  const float inv = 1.0f / fmaxf(sqrtf(red[0]), 1e-12f);
  const float vn = v * inv;
  rnorm[b * 256 + t] = vn;
  vtmp[t] = vn;
  __syncthreads();
  if (t < 128) rnbf[b * 128 + t] = pk_bf16(vtmp[2 * t], vtmp[2 * t + 1]);
}

// ---------------------------------------------------------------- FUSED MFMA sims (register-staged, 1 barrier / 2 subs)
__global__ __launch_bounds__(512, 4)
void sims_fused(const uint32_t* __restrict__ rnbf, const float* __restrict__ bank,
                const float* __restrict__ vals, float* __restrict__ cand_s,
                int* __restrict__ cand_i) {
  __shared__ __align__(16) unsigned short tB[4][16 * 256];  // 4 x 8 KB
  __shared__ float valsL[CHUNK];                            // 4 KB

  const int t = threadIdx.x;
  const int lane = t & 63;
  const int w = t >> 6;            // wave 0..7 -> batch rows w*16..w*16+15
  const int fr = lane & 15;
  const int fq = lane >> 4;        // 0..3 (k-group)
  const int cbase = blockIdx.x * CHUNK;

  // ---- B-frags (one 16-row batch set per wave) from bf16 rnorm
  bf16x8 Bf[8];
  {
    const uint4* rp = reinterpret_cast<const uint4*>(rnbf + (size_t)(w * 16 + fr) * 128);
#pragma unroll
    for (int ks = 0; ks < 8; ++ks) {
      uint4 u = rp[ks * 4 + fq];
      Bf[ks] = *reinterpret_cast<bf16x8*>(&u);
    }
  }

  float ts[4]; int ti[4];
#pragma unroll
  for (int q = 0; q < 4; ++q) { ts[q] = -INFINITY; ti[q] = 0x7ffffff0 + q; }

  float4 pA0, pA1, pB0, pB1;       // register staging (2 subs in flight)

  auto loadrow = [&](int m) -> float4 {
    if (m > M_TOT - 1) m = M_TOT - 1;          // clamp: row skipped in epilogue
    return *reinterpret_cast<const float4*>(bank + (size_t)m * 256 + lane * 4);
  };
  auto issueA = [&](int s) {
    pA0 = loadrow(cbase + s * 16 + w * 2);
    pA1 = loadrow(cbase + s * 16 + w * 2 + 1);
  };
  auto issueB = [&](int s) {
    pB0 = loadrow(cbase + s * 16 + w * 2);
    pB1 = loadrow(cbase + s * 16 + w * 2 + 1);
  };
  auto convrow = [&](const float4 v, int s, int r, unsigned short* dst) {
    float ssq = v.x * v.x + v.y * v.y + v.z * v.z + v.w * v.w;
#pragma unroll
    for (int msk = 1; msk < 64; msk <<= 1) ssq += __shfl_xor(ssq, msk);
    const float vv = valsL[s * 16 + r];
    const float wsc = (vv + 1e-8f) / fmaxf(sqrtf(ssq), 1e-12f);
    uint2 p;
    p.x = pk_bf16(v.x * wsc, v.y * wsc);
    p.y = pk_bf16(v.z * wsc, v.w * wsc);
    const int c = lane >> 1, h = lane & 1;
    *reinterpret_cast<uint2*>(
        reinterpret_cast<char*>(dst) + r * 512 + (((c ^ (r & 7)) << 4) + h * 8)) = p;
  };
  auto mfma_epi = [&](int s, const unsigned short* tc) {
    f32x4 acc = (f32x4){0.f, 0.f, 0.f, 0.f};
#pragma unroll
    for (int ks = 0; ks < 8; ++ks) {
      const int kc = ks * 4 + fq;
      const bf16x8 a = *reinterpret_cast<const bf16x8*>(
          tc + fr * 256 + ((kc ^ (fr & 7)) << 3));
      acc = __builtin_amdgcn_mfma_f32_16x16x32_bf16(a, Bf[ks], acc, 0, 0, 0);
    }
    const int m_base = cbase + s * 16;
#pragma unroll
    for (int j = 0; j < 4; ++j) {
      const int mm = m_base + fq * 4 + j;
      if (mm < M_TOT) ins4_nd(acc[j], mm, ts, ti);
    }
  };

  // ---- prologue: vals -> LDS (2 gload_lds4/wave), subs 0,1 -> registers
#pragma unroll
  for (int j = 0; j < 2; ++j) {
    const int seg = w * 2 + j;                   // 0..15, 64 floats each
    int mi = cbase + seg * 64 + lane;
    if (mi > M_TOT - 1) mi = M_TOT - 1;
    load_lds4(vals + mi, reinterpret_cast<char*>(valsL) + seg * 256);
  }
  issueA(0); issueB(1);
  asm volatile("s_waitcnt vmcnt(0)" ::: "memory");   // one-time full drain: valsL + pA/pB
  __builtin_amdgcn_sched_barrier(0);
  __builtin_amdgcn_s_barrier();                      // valsL visible

  for (int s2 = 0; s2 < NSUB; s2 += 2) {
    const int pr = (s2 >> 1) & 1;                // buffer pair 0 or 1
    unsigned short* t0 = tB[pr * 2];
    unsigned short* t1 = tB[pr * 2 + 1];
    // ---- convert both staged subs into this pair
    convrow(pA0, s2, w * 2, t0);
    convrow(pA1, s2, w * 2 + 1, t0);
    convrow(pB0, s2 + 1, w * 2, t1);
    convrow(pB1, s2 + 1, w * 2 + 1, t1);
    // ---- refill registers for subs s2+2, s2+3 (land under MFMA + next convert)
    if (s2 + 2 < NSUB) issueA(s2 + 2);
    if (s2 + 3 < NSUB) issueB(s2 + 3);
    asm volatile("s_waitcnt lgkmcnt(0)" ::: "memory");
    __builtin_amdgcn_sched_barrier(0);
    __builtin_amdgcn_s_barrier();                // pair visible to all waves
    mfma_epi(s2, t0);
    mfma_epi(s2 + 1, t1);
  }

  // merge the 4 fq-lane groups sharing each batch row (snapshot butterfly)
#pragma unroll
  for (int mask = 16; mask < 64; mask <<= 1) {
    float os[4]; int oi[4];
#pragma unroll
    for (int q = 0; q < 4; ++q) {
      os[q] = __shfl_xor(ts[q], mask);
      oi[q] = __shfl_xor(ti[q], mask);
    }
#pragma unroll
    for (int q = 0; q < 4; ++q) ins4(os[q], oi[q], ts, ti);
  }
  if (fq == 0) {
    const int b = w * 16 + fr;
    const size_t base = ((size_t)b * NCHUNK + blockIdx.x) * 4;
#pragma unroll
    for (int q = 0; q < 4; ++q) { cand_s[base + q] = ts[q]; cand_i[base + q] = ti[q]; }
  }
}

// ---------------------------------------------------------------- merge + rescore + fuse + policy heads (fused)
__global__ __launch_bounds__(256)
void topk_heads(const float* __restrict__ cand_s, const int* __restrict__ cand_i,
                const float* __restrict__ bank, const float* __restrict__ vals,
                const float* __restrict__ rnorm, const float* __restrict__ r0,
                const float* __restrict__ Wc, const float* __restrict__ bc,
                const float* __restrict__ Wd, const float* __restrict__ bd,
                const float* __restrict__ Wsw, const float* __restrict__ bsw,
                const float* __restrict__ Wv, const float* __restrict__ bv,
                float* __restrict__ out) {
  const int b = blockIdx.x, t = threadIdx.x;
  __shared__ float rnL[256];
  __shared__ float ss[2048];
  __shared__ int   si[2048];
  __shared__ int   g8[8];
  __shared__ float sc8[8];
  __shared__ int   gidx[3];
  __shared__ float rl[256];
  __shared__ float red[256];
  __shared__ float hd[8];

  rnL[t] = rnorm[b * 256 + t];

  float ts[8]; int ti[8];
#pragma unroll
  for (int q = 0; q < 8; ++q) { ts[q] = -INFINITY; ti[q] = 0x7fffff00 + t * 8 + q; }
  const int n = NCHUNK * 4;
  const size_t base = (size_t)b * n;
  for (int c = t; c < n; c += 256) ins8(cand_s[base + c], cand_i[base + c], ts, ti);
#pragma unroll
  for (int q = 0; q < 8; ++q) { ss[t * 8 + q] = ts[q]; si[t * 8 + q] = ti[q]; }
  __syncthreads();

  if (t < 64) {
    float ms[8]; int mi[8];
#pragma unroll
    for (int q = 0; q < 8; ++q) { ms[q] = -INFINITY; mi[q] = 0x7ffffe00 + t * 8 + q; }
    for (int c = t * 32; c < t * 32 + 32; ++c) ins8(ss[c], si[c], ms, mi);
#pragma unroll
    for (int mask = 1; mask < 64; mask <<= 1) {
      float os[8]; int oi[8];
#pragma unroll
      for (int q = 0; q < 8; ++q) { os[q] = __shfl_xor(ms[q], mask); oi[q] = __shfl_xor(mi[q], mask); }
#pragma unroll
      for (int q = 0; q < 8; ++q) ins8(os[q], oi[q], ms, mi);
    }
    if (t == 0) {
#pragma unroll
      for (int q = 0; q < 8; ++q) g8[q] = mi[q];
    }
  }
  __syncthreads();

  {
    const int c = t >> 5, g = t & 31;
    const int id = g8[c];
    float ssq = 0.0f, dt = 0.0f;
    if (id < M_TOT) {
      const float4* bp = reinterpret_cast<const float4*>(bank + (size_t)id * 256);
      const float4 x0 = bp[g * 2], x1 = bp[g * 2 + 1];
      const float4 r0v = *reinterpret_cast<const float4*>(&rnL[g * 8]);
      const float4 r1v = *reinterpret_cast<const float4*>(&rnL[g * 8 + 4]);
      ssq = x0.x*x0.x + x0.y*x0.y + x0.z*x0.z + x0.w*x0.w +
            x1.x*x1.x + x1.y*x1.y + x1.z*x1.z + x1.w*x1.w;
      dt  = x0.x*r0v.x + x0.y*r0v.y + x0.z*r0v.z + x0.w*r0v.w +
            x1.x*r1v.x + x1.y*r1v.y + x1.z*r1v.z + x1.w*r1v.w;
    }
#pragma unroll
    for (int mask = 1; mask < 32; mask <<= 1) { ssq += __shfl_xor(ssq, mask); dt += __shfl_xor(dt, mask); }
    if (g == 0)
      sc8[c] = (id < M_TOT)
                 ? dt * (1.0f / fmaxf(sqrtf(ssq), 1e-12f)) * (vals[id] + 1e-8f)
                 : -INFINITY;
  }
  __syncthreads();

  if (t == 0) {
    float gs[3] = {-INFINITY, -INFINITY, -INFINITY};
    int gi[3] = {0x7fffffff, 0x7ffffffe, 0x7ffffffd};
#pragma unroll
    for (int q = 0; q < 8; ++q) ins3(sc8[q], g8[q], gs, gi);
    gidx[0] = gi[0]; gidx[1] = gi[1]; gidx[2] = gi[2];
  }
  __syncthreads();

  {
    const int i0 = gidx[0], i1 = gidx[1], i2 = gidx[2];
    const float retr = (bank[(size_t)i0 * 256 + t] + bank[(size_t)i1 * 256 + t] +
                        bank[(size_t)i2 * 256 + t]) / 3.0f;
    rl[t] = 0.5f * r0[b * 256 + t] + 0.5f * retr;
  }
  __syncthreads();

  float y = bd[t];
#pragma unroll 8
  for (int k = 0; k < 256; ++k) y += rl[k] * Wd[k * 256 + t];
  red[t] = y * y;
  if (t < 4) {
    float a;
    if (t == 0) { a = bc[0]; for (int k = 0; k < 256; ++k) a += rl[k] * Wc[2 * k]; }
    else if (t == 1) { a = bc[1]; for (int k = 0; k < 256; ++k) a += rl[k] * Wc[2 * k + 1]; }
    else if (t == 2) { a = bsw[0]; for (int k = 0; k < 256; ++k) a += rl[k] * Wsw[k]; }
    else { a = bv[0]; for (int k = 0; k < 256; ++k) a += rl[k] * Wv[k]; }
    hd[t] = a;
  }
  __syncthreads();
  for (int s = 128; s > 0; s >>= 1) { if (t < s) red[t] += red[t + s]; __syncthreads(); }
  const float dirn = y / fmaxf(sqrtf(red[0]), 1e-12f);
  if (t == 0) {
    const float l0 = hd[0], l1 = hd[1];
    uint32_t a0, a1, c0, c1;
    threefry2x32(0u, 1u, 0u, (uint32_t)(2 * b), a0, a1);
    threefry2x32(0u, 1u, 0u, (uint32_t)(2 * b + 1), c0, c1);
    const float g0 = gumbel_from_bits(a0 ^ a1);
    const float g1 = gumbel_from_bits(c0 ^ c1);
    const int act = (l1 + g1 > l0 + g0) ? 1 : 0;
    const float mx = fmaxf(l0, l1);
    const float lse = mx + logf(expf(l0 - mx) + expf(l1 - mx));
    const float lp0 = l0 - lse, lp1 = l1 - lse;
    out[OFF_ACT + b] = (float)act;
    out[OFF_LP + b] = act ? lp1 : lp0;
    out[OFF_VAL + b] = hd[3];
    out[OFF_ENT + b] = -(expf(lp0) * lp0 + expf(lp1) * lp1);
    hd[4] = 2.0f / (1.0f + expf(-hd[2]));
  }
  __syncthreads();
  out[OFF_POS + b * 256 + t] = rl[t] + hd[4] * dirn;
}

// ---------------------------------------------------------------- launch
extern "C" void kernel_launch(void* const* d_in, const int* in_sizes, int n_in,
                              void* d_out, int out_size, void* d_ws, size_t ws_size,
                              hipStream_t stream) {
  const float* state = (const float*)d_in[0];
  const float* bank  = (const float*)d_in[1];
  const float* vals  = (const float*)d_in[2];
  const float* W1  = (const float*)d_in[3];
  const float* b1  = (const float*)d_in[4];
  const float* W2  = (const float*)d_in[5];
  const float* b2  = (const float*)d_in[6];
  const float* Wc  = (const float*)d_in[7];
  const float* bc  = (const float*)d_in[8];
  const float* Wd  = (const float*)d_in[9];
  const float* bd  = (const float*)d_in[10];
  const float* Wsw = (const float*)d_in[11];
  const float* bsw = (const float*)d_in[12];
  const float* Wv  = (const float*)d_in[13];
  const float* bv  = (const float*)d_in[14];
  const float* T1w = (const float*)d_in[15];
  const float* t1b = (const float*)d_in[16];
  const float* T2w = (const float*)d_in[17];
  const float* t2b = (const float*)d_in[18];
  float* out = (float*)d_out;
  float* ws = (float*)d_ws;

  // workspace layout (floats). regA (4,194,304) holds W1 partials (16x131072)
  // and later T2 partials (8x524288); cs/ci overlap its head (dead interval:
  // written by sims_fused after combine_z<16> consumed W1 partials, consumed
  // by topk_heads before the T2 gemm writes regA).
  float* regA = ws;                   // 4,194,304
  float* cs   = ws;                   // 250,368 (128*489*4)  [overlaps regA]
  int*   ci   = (int*)(ws + 250368);  // 250,368              [overlaps regA]
  float* h1   = ws + 4194304;         // 131,072
  float* regC = ws + 4325376;         // 1,048,576 (W2 partials 8x32768 / T1 partials 8x131072)
  float* r0   = ws + 5373952;         // 32,768
  float* rnm  = ws + 5406720;         // 32,768
  float* h2   = ws + 5439488;         // 131,072
  uint32_t* rnbf = (uint32_t*)(ws + 5570560);   // 16,384 u32 (bf16 rnorm)

  // state_projection: H -> H/4 (relu) -> R  (deep K-split: latency-bound)
  gemm_tile<<<dim3(16, 2, 16), 256, 0, stream>>>(state, W1, regA, 128, 1024, 4096, 256);
  combine_z<16, true><<<512, 256, 0, stream>>>(regA, b1, h1, 131072, 1023);
  gemm_tile<<<dim3(4, 2, 8), 256, 0, stream>>>(h1, W2, regC, 128, 256, 1024, 128);
  combine_r0<<<128, 256, 0, stream>>>(regC, b2, r0, rnm, rnbf);
  // retrieval: single-pass fused sims (register-staged, 1 barrier / 2 subs)
  sims_fused<<<NCHUNK, 512, 0, stream>>>(rnbf, bank, vals, cs, ci);
  topk_heads<<<128, 256, 0, stream>>>(cs, ci, bank, vals, rnm, r0,
                                      Wc, bc, Wd, bd, Wsw, bsw, Wv, bv, out);
  // thought_projection: R -> H/4 (relu) -> H  (deep K-split)
  gemm_tile<<<dim3(16, 2, 8), 256, 0, stream>>>(out + OFF_POS, T1w, regC, 128, 1024, 256, 32);
  combine_z<8, true><<<512, 256, 0, stream>>>(regC, t1b, h2, 131072, 1023);
  gemm_tile<<<dim3(64, 2, 8), 256, 0, stream>>>(h2, T2w, regA, 128, 4096, 1024, 128);
  combine_z<8, false><<<2048, 256, 0, stream>>>(regA, t2b, out + OFF_LATENT, 524288, 4095);
}